// Round 5
// baseline (8280.551 us; speedup 1.0000x reference)
//
#include <hip/hip_runtime.h>
#include <math.h>

#define NB   64      // batch
#define LL   196     // regions
#define AD   512     // image feat dim
#define HD   512     // hidden
#define VD   30000   // vocab
#define TS   20      // steps
#define G4   2048    // 4*H
#define NBL  235     // ceil(30000/128) logits tiles
#define NC2  (NBL * 2)   // top-2 candidates per tile per row = 470
#define NBLK 256     // persistent grid size

typedef __bf16 bf16x8 __attribute__((ext_vector_type(8)));
typedef float  f32x4  __attribute__((ext_vector_type(4)));

__device__ __forceinline__ float fast_tanh(float x) {
    float e = __builtin_exp2f(x * 2.8853900817779268f);   // exp(2x)
    return 1.0f - 2.0f / (e + 1.0f);
}
__device__ __forceinline__ float fast_sigmoid(float x) {
    return 1.0f / (1.0f + __builtin_exp2f(-x * 1.4426950408889634f));
}
__device__ __forceinline__ float fast_exp(float x) {
    return __builtin_exp2f(x * 1.4426950408889634f);
}
__device__ __forceinline__ unsigned short f2bf(float f) {   // RNE fp32->bf16
    unsigned int u = __float_as_uint(f);
    u += 0x7fffu + ((u >> 16) & 1u);
    return (unsigned short)(u >> 16);
}
// async global->LDS DMA, 16B per lane; lds base must be wave-uniform
__device__ __forceinline__ void gload_lds16(const void* g, void* l) {
    __builtin_amdgcn_global_load_lds((const __attribute__((address_space(1))) void*)g,
                                     (__attribute__((address_space(3))) void*)l, 16, 0, 0);
}
// merge two (top1, top2) candidate pairs, tie-break: smaller index wins
__device__ __forceinline__ void top2_merge(float& v1, int& i1, float& v2, int& i2,
                                           float ov1, int oi1, float ov2, int oi2) {
    if (ov1 > v1 || (ov1 == v1 && oi1 < i1)) {
        float sv = v1; int si = i1;
        v1 = ov1; i1 = oi1;
        if (ov2 > sv || (ov2 == sv && oi2 < si)) { v2 = ov2; i2 = oi2; }
        else { v2 = sv; i2 = si; }
    } else {
        if (ov1 > v2 || (ov1 == v2 && oi1 < i2)) { v2 = ov1; i2 = oi1; }
    }
}

// device-scope grid barrier: monotonic counter, target = NBLK * epoch.
// tid0: device fence + agent-scope RMW, then acquire-spin. All blocks resident
// (256 blocks, 37KB LDS, <=4 blocks/CU capacity) so no deadlock.
__device__ __forceinline__ void gridbar(unsigned* cnt, unsigned target) {
    __syncthreads();
    if (threadIdx.x == 0) {
        __threadfence();   // publish this block's writes at device scope
        __hip_atomic_fetch_add(cnt, 1u, __ATOMIC_ACQ_REL, __HIP_MEMORY_SCOPE_AGENT);
        while (__hip_atomic_load(cnt, __ATOMIC_ACQUIRE, __HIP_MEMORY_SCOPE_AGENT) < target) {
            __builtin_amdgcn_s_sleep(2);
        }
    }
    __syncthreads();
}

// ---------------- precompute: mean over L, h0/c0, tok init, barrier reset ----------------
__global__ void k_init(const float* __restrict__ hl, const float* __restrict__ Wh0,
                       const float* __restrict__ bh0, const float* __restrict__ Wc0,
                       const float* __restrict__ bc0, float* __restrict__ h_ws,
                       float* __restrict__ c_ws, int* __restrict__ tok_ws,
                       unsigned* __restrict__ barcnt) {
    __shared__ float mean_s[AD];
    int n = blockIdx.x, tid = threadIdx.x;
    if (n == 0 && tid == 0) *barcnt = 0u;   // replay-safe barrier reset
    for (int a = tid; a < AD; a += 256) {
        float acc = 0.f;
        const float* p = hl + ((size_t)n * LL) * AD + a;
        for (int l = 0; l < LL; ++l) acc += p[(size_t)l * AD];
        mean_s[a] = acc / 196.0f;
    }
    __syncthreads();
    for (int hh = tid; hh < HD; hh += 256) {
        float ah = bh0[hh], ac = bc0[hh];
        for (int k = 0; k < AD; ++k) {
            float m = mean_s[k];
            ah = fmaf(m, Wh0[k * HD + hh], ah);
            ac = fmaf(m, Wc0[k * HD + hh], ac);
        }
        h_ws[n * HD + hh] = fast_tanh(ah);
        c_ws[n * HD + hh] = fast_tanh(ac);
    }
    if (tid == 0) tok_ws[n] = 1;  // START
}

// ---------------- precompute: hl_Wa = hl @ Wa  (12544x512 @ 512x512) ----------------
__global__ void k_hlwa(const float* __restrict__ Amat, const float* __restrict__ Bmat,
                       float* __restrict__ Cmat) {
    __shared__ __attribute__((aligned(16))) float xt[64 * 64];  // (k, m) skewed
    __shared__ __attribute__((aligned(16))) float bs[64 * 68];  // (k, j) stride-68
    int tid = threadIdx.x;
    int lane16 = tid & 15, rowg = tid >> 4;
    int m0 = blockIdx.x * 64, jb = blockIdx.y * 64;
    float acc[4][4] = {};
    for (int ch = 0; ch < 8; ++ch) {
        int kbase = ch * 64;
        __syncthreads();
        for (int it = 0; it < 4; ++it) {
            int k4 = tid & 15;
            int nrow = (tid >> 4) + it * 16;
            float4 v = *(const float4*)&Amat[(size_t)(m0 + nrow) * 512 + kbase + k4 * 4];
            int col = (nrow + k4 * 4) & 63;
            xt[(k4 * 4 + 0) * 64 + col] = v.x;
            xt[(k4 * 4 + 1) * 64 + col] = v.y;
            xt[(k4 * 4 + 2) * 64 + col] = v.z;
            xt[(k4 * 4 + 3) * 64 + col] = v.w;
        }
        for (int it = 0; it < 4; ++it) {
            int r = it * 16 + (tid >> 4);
            int c4 = (tid & 15) * 4;
            *(float4*)&bs[r * 68 + c4] = *(const float4*)&Bmat[(size_t)(kbase + r) * 512 + jb + c4];
        }
        __syncthreads();
#pragma unroll 8
        for (int kk = 0; kk < 64; ++kk) {
            float4 w4 = *(const float4*)&bs[kk * 68 + lane16 * 4];
            float4 h4 = *(const float4*)&xt[kk * 64 + ((rowg * 4 + (kk & ~3)) & 63)];
            float hv[4] = {h4.x, h4.y, h4.z, h4.w};
            float wv[4] = {w4.x, w4.y, w4.z, w4.w};
#pragma unroll
            for (int r = 0; r < 4; ++r)
#pragma unroll
                for (int j = 0; j < 4; ++j) acc[r][j] = fmaf(hv[r], wv[j], acc[r][j]);
        }
    }
    for (int r = 0; r < 4; ++r) {
        float4 o = {acc[r][0], acc[r][1], acc[r][2], acc[r][3]};
        *(float4*)&Cmat[(size_t)(m0 + rowg * 4 + r) * 512 + jb + lane16 * 4] = o;
    }
}

// ---------------- one-shot: pack Wout (fp32 [512][30000]) -> bf16 B-fragments ----------
__global__ void k_wcvt(const float* __restrict__ Wout, unsigned short* __restrict__ WoutB) {
    int id = blockIdx.x * 256 + threadIdx.x;      // 0 .. 1,920,000-1
    int lane = id & 63;
    int kb = (id >> 6) & 15;
    int vb = id >> 10;
    int v  = vb * 16 + (lane & 15);
    int k0 = kb * 32 + (lane >> 4) * 8;
    unsigned int pk[4];
#pragma unroll
    for (int p = 0; p < 4; ++p) {
        unsigned int lo = f2bf(Wout[(size_t)(k0 + 2 * p) * VD + v]);
        unsigned int hi = f2bf(Wout[(size_t)(k0 + 2 * p + 1) * VD + v]);
        pk[p] = lo | (hi << 16);
    }
    *(uint4*)&WoutB[(size_t)id * 8] = make_uint4(pk[0], pk[1], pk[2], pk[3]);
}

// ================= device phase functions (math verbatim from verified kernels) =========

// hua: b in 0..63
__device__ __forceinline__ void do_hua(int b, int tid, float* smem,
        const float* __restrict__ h_ws, const float* __restrict__ Ua,
        float* __restrict__ hua_part) {
    float* xt = smem;          // 4096 floats
    float* us = smem + 4096;   // 4352 floats
    int lane16 = tid & 15, rowg = tid >> 4;
    int s = b & 7, jt = b >> 3;
    int jb = jt * 64, kbase = s * 64;
    float acc[4][4] = {};
    for (int it = 0; it < 4; ++it) {
        int k4 = tid & 15;
        int nrow = (tid >> 4) + it * 16;
        float4 v = *(const float4*)&h_ws[nrow * 512 + kbase + k4 * 4];
        int col = (nrow + k4 * 4) & 63;
        xt[(k4 * 4 + 0) * 64 + col] = v.x;
        xt[(k4 * 4 + 1) * 64 + col] = v.y;
        xt[(k4 * 4 + 2) * 64 + col] = v.z;
        xt[(k4 * 4 + 3) * 64 + col] = v.w;
    }
    for (int it = 0; it < 4; ++it) {
        int r = it * 16 + (tid >> 4);
        int c4 = (tid & 15) * 4;
        *(float4*)&us[r * 68 + c4] = *(const float4*)&Ua[(size_t)(kbase + r) * 512 + jb + c4];
    }
    __syncthreads();
#pragma unroll 8
    for (int kk = 0; kk < 64; ++kk) {
        float4 w4 = *(const float4*)&us[kk * 68 + lane16 * 4];
        float4 h4 = *(const float4*)&xt[kk * 64 + ((rowg * 4 + (kk & ~3)) & 63)];
        float hv[4] = {h4.x, h4.y, h4.z, h4.w};
        float wv[4] = {w4.x, w4.y, w4.z, w4.w};
#pragma unroll
        for (int r = 0; r < 4; ++r)
#pragma unroll
            for (int j = 0; j < 4; ++j) acc[r][j] = fmaf(hv[r], wv[j], acc[r][j]);
    }
    float* gp = hua_part + (size_t)s * NB * HD;
    for (int r = 0; r < 4; ++r) {
        float4 o = {acc[r][0], acc[r][1], acc[r][2], acc[r][3]};
        *(float4*)&gp[(size_t)(rowg * 4 + r) * 512 + jb + lane16 * 4] = o;
    }
}

// att_e: b in 0..191 -> n = b&63, q = b>>6 (3-way row split; per-l math identical)
__device__ __forceinline__ void do_att_e(int b, int tid,
        const float* __restrict__ hlwa, const float* __restrict__ hua_part,
        const float* __restrict__ ba, const float* __restrict__ va,
        float* __restrict__ e_ws) {
    int n = b & 63, q = b >> 6;
    int wave = tid >> 6, lane = tid & 63;
    float4 ua_a = *(const float4*)&ba[lane * 4];
    float4 ua_b = *(const float4*)&ba[256 + lane * 4];
    for (int s = 0; s < 8; ++s) {
        const float* p = hua_part + (size_t)s * NB * HD + n * HD;
        float4 pa = *(const float4*)&p[lane * 4];
        float4 pb = *(const float4*)&p[256 + lane * 4];
        ua_a.x += pa.x; ua_a.y += pa.y; ua_a.z += pa.z; ua_a.w += pa.w;
        ua_b.x += pb.x; ua_b.y += pb.y; ua_b.z += pb.z; ua_b.w += pb.w;
    }
    float4 va_a = *(const float4*)&va[lane * 4];
    float4 va_b = *(const float4*)&va[256 + lane * 4];
    int lstart = q * 66, lend = (q == 2) ? LL : (q * 66 + 66);
    for (int l = lstart + wave; l < lend; l += 4) {
        const float* base = hlwa + ((size_t)n * LL + l) * HD;
        float4 xa = *(const float4*)&base[lane * 4];
        float4 xb = *(const float4*)&base[256 + lane * 4];
        float s = 0.f;
        s = fmaf(fast_tanh(xa.x + ua_a.x), va_a.x, s);
        s = fmaf(fast_tanh(xa.y + ua_a.y), va_a.y, s);
        s = fmaf(fast_tanh(xa.z + ua_a.z), va_a.z, s);
        s = fmaf(fast_tanh(xa.w + ua_a.w), va_a.w, s);
        s = fmaf(fast_tanh(xb.x + ua_b.x), va_b.x, s);
        s = fmaf(fast_tanh(xb.y + ua_b.y), va_b.y, s);
        s = fmaf(fast_tanh(xb.z + ua_b.z), va_b.z, s);
        s = fmaf(fast_tanh(xb.w + ua_b.w), va_b.w, s);
        for (int m = 1; m < 64; m <<= 1) s += __shfl_xor(s, m, 64);
        if (lane == 0) e_ws[n * LL + l] = s;
    }
}

// soft_z: n in 0..63
__device__ __forceinline__ void do_soft_z(int n, int tid, float* smem,
        const float* __restrict__ e_ws, const float* __restrict__ hl,
        const float* __restrict__ h_ws, const float* __restrict__ Wb,
        const float* __restrict__ bb, float* __restrict__ z_ws) {
    float* red = smem;            // 256
    float* alpha = smem + 256;    // 256
    float* zs = smem + 512;       // 512
    // beta at smem[1024]
    float ev = (tid < LL) ? e_ws[n * LL + tid] : -INFINITY;
    red[tid] = ev;
    __syncthreads();
    for (int s = 128; s > 0; s >>= 1) {
        if (tid < s) red[tid] = fmaxf(red[tid], red[tid + s]);
        __syncthreads();
    }
    float m = red[0];
    __syncthreads();
    float a = (tid < LL) ? fast_exp(ev - m) : 0.f;
    red[tid] = a;
    __syncthreads();
    for (int s = 128; s > 0; s >>= 1) {
        if (tid < s) red[tid] += red[tid + s];
        __syncthreads();
    }
    float sum = red[0];
    alpha[tid] = a / sum;
    __syncthreads();
    float bp = h_ws[n * HD + tid] * Wb[tid] + h_ws[n * HD + 256 + tid] * Wb[256 + tid];
    red[tid] = bp;
    __syncthreads();
    for (int s = 128; s > 0; s >>= 1) {
        if (tid < s) red[tid] += red[tid + s];
        __syncthreads();
    }
    if (tid == 0) smem[1024] = fast_sigmoid(red[0] + bb[0]);
    int lq = tid >> 7, ai = tid & 127;
    const float* base = hl + ((size_t)n * LL) * AD + ai * 4;
    float4 acc4 = {0.f, 0.f, 0.f, 0.f};
    int l0 = lq * 98, l1 = l0 + 98;
    for (int l = l0; l < l1; ++l) {
        float al = alpha[l];
        float4 v = *(const float4*)&base[(size_t)l * AD];
        acc4.x = fmaf(al, v.x, acc4.x);
        acc4.y = fmaf(al, v.y, acc4.y);
        acc4.z = fmaf(al, v.z, acc4.z);
        acc4.w = fmaf(al, v.w, acc4.w);
    }
    if (lq == 1) *(float4*)&zs[ai * 4] = acc4;
    __syncthreads();
    if (lq == 0) {
        float4 o = *(const float4*)&zs[ai * 4];
        float b = smem[1024];
        o.x = (o.x + acc4.x) * b;
        o.y = (o.y + acc4.y) * b;
        o.z = (o.z + acc4.z) * b;
        o.w = (o.w + acc4.w) * b;
        *(float4*)&z_ws[n * AD + ai * 4] = o;
    }
}

// gates: b in 0..255
__device__ __forceinline__ void do_gates(int b, int tid, float* smem,
        const float* __restrict__ z_ws, const float* __restrict__ emb,
        const int* __restrict__ tok_ws, const float* __restrict__ h_ws,
        const float* __restrict__ Wx, const float* __restrict__ Wh,
        float* __restrict__ gates_part) {
    float* xt = smem;          // 4096
    float* wsl = smem + 4096;  // 4352
    int lane16 = tid & 15, rowg = tid >> 4;
    int s = b & 7, jt = b >> 3;
    int jb = jt * 64;
    float acc[4][4] = {};
    for (int ch = 0; ch < 3; ++ch) {
        int kbase = s * 192 + ch * 64;
        __syncthreads();
        for (int it = 0; it < 4; ++it) {
            int nrow = (tid >> 4) + it * 16;
            int k4 = tid & 15;
            int gk = kbase + k4 * 4;
            const float* src;
            if (gk < 512)       src = &z_ws[nrow * 512 + gk];
            else if (gk < 1024) src = &emb[(size_t)tok_ws[nrow] * 512 + (gk - 512)];
            else                src = &h_ws[nrow * 512 + (gk - 1024)];
            float4 v = *(const float4*)src;
            int col = (nrow + k4 * 4) & 63;
            xt[(k4 * 4 + 0) * 64 + col] = v.x;
            xt[(k4 * 4 + 1) * 64 + col] = v.y;
            xt[(k4 * 4 + 2) * 64 + col] = v.z;
            xt[(k4 * 4 + 3) * 64 + col] = v.w;
        }
        for (int it = 0; it < 4; ++it) {
            int r = it * 16 + (tid >> 4);
            int gk = kbase + r;
            const float* wrow = (gk < 1024) ? &Wx[(size_t)gk * G4] : &Wh[(size_t)(gk - 1024) * G4];
            int c4 = (tid & 15) * 4;
            *(float4*)&wsl[r * 68 + c4] = *(const float4*)&wrow[jb + c4];
        }
        __syncthreads();
#pragma unroll 8
        for (int kk = 0; kk < 64; ++kk) {
            float4 w4 = *(const float4*)&wsl[kk * 68 + lane16 * 4];
            float4 h4 = *(const float4*)&xt[kk * 64 + ((rowg * 4 + (kk & ~3)) & 63)];
            float hv[4] = {h4.x, h4.y, h4.z, h4.w};
            float wv[4] = {w4.x, w4.y, w4.z, w4.w};
#pragma unroll
            for (int r = 0; r < 4; ++r)
#pragma unroll
                for (int j = 0; j < 4; ++j) acc[r][j] = fmaf(hv[r], wv[j], acc[r][j]);
        }
    }
    float* gp = gates_part + (size_t)s * NB * G4;
    for (int r = 0; r < 4; ++r) {
        float4 o = {acc[r][0], acc[r][1], acc[r][2], acc[r][3]};
        *(float4*)&gp[(size_t)(rowg * 4 + r) * G4 + jb + lane16 * 4] = o;
    }
}

// lstm: b in 0..127
__device__ __forceinline__ void do_lstm(int b, int tid,
        const float* __restrict__ gates_part, const float* __restrict__ b_lstm,
        float* __restrict__ h_ws, float* __restrict__ c_ws,
        unsigned short* __restrict__ hB) {
    int idx = b * 256 + tid;  // 0..32767
    int n = idx >> 9, hh = idx & 511;
    float ig = b_lstm[hh], fg = b_lstm[512 + hh], gg = b_lstm[1024 + hh], og = b_lstm[1536 + hh];
    for (int s = 0; s < 8; ++s) {
        const float* gp = gates_part + (size_t)s * NB * G4 + (size_t)n * G4;
        ig += gp[hh]; fg += gp[512 + hh]; gg += gp[1024 + hh]; og += gp[1536 + hh];
    }
    float c = c_ws[idx];
    float cn = fast_sigmoid(fg) * c + fast_sigmoid(ig) * fast_tanh(gg);
    float hn = fast_sigmoid(og) * fast_tanh(cn);
    c_ws[idx] = cn;
    h_ws[idx] = hn;
    int mb = n >> 4, kb = hh >> 5;
    int lane = (n & 15) + ((hh >> 3) & 3) * 16;
    hB[(((size_t)mb * 16 + kb) * 64 + lane) * 8 + (hh & 7)] = f2bf(hn);
}

// logits: one 128-col vocab tile (0..234); hB staged in two 32KB LDS halves
__device__ __forceinline__ void do_logits(int tile, int tid, float* smem,
        const unsigned short* __restrict__ hB, const unsigned short* __restrict__ WoutB,
        const float* __restrict__ bout, float* __restrict__ pval, int* __restrict__ pidx) {
    unsigned short* hs = (unsigned short*)smem;   // 32 KB = 2048 16B-slots
    float* sv1 = smem + 8192; float* sv2 = smem + 8448;
    int* si1 = (int*)(smem + 8704); int* si2 = (int*)(smem + 8960);
    int w = tid >> 6, lane = tid & 63;
    int jb = tile * 128;
    if (jb > VD - 128) jb = VD - 128;
    int vbw = (jb >> 4) + w * 2;
    const bf16x8* wP = (const bf16x8*)WoutB;
    const bf16x8* hP = (const bf16x8*)hs;
    f32x4 acc[2][4] = {};
    for (int hf = 0; hf < 2; ++hf) {
        __syncthreads();   // prior hs/sv use complete before restage
#pragma unroll
        for (int i = 0; i < 8; ++i) {
            int sbase = i * 256 + w * 64;
            int mb = sbase >> 9, kb2 = (sbase >> 6) & 7;
            int gslot = (mb * 16 + hf * 8 + kb2) * 64;
            gload_lds16(&hB[(size_t)(gslot + lane) * 8], &hs[(size_t)sbase * 8]);
        }
        __syncthreads();   // drains DMA
#pragma unroll 2
        for (int kb2 = 0; kb2 < 8; ++kb2) {
            int kb = hf * 8 + kb2;
            bf16x8 b0 = wP[((size_t)vbw * 16 + kb) * 64 + lane];
            bf16x8 b1 = wP[((size_t)(vbw + 1) * 16 + kb) * 64 + lane];
            bf16x8 a0 = hP[(0 * 8 + kb2) * 64 + lane];
            bf16x8 a1 = hP[(1 * 8 + kb2) * 64 + lane];
            bf16x8 a2 = hP[(2 * 8 + kb2) * 64 + lane];
            bf16x8 a3 = hP[(3 * 8 + kb2) * 64 + lane];
            acc[0][0] = __builtin_amdgcn_mfma_f32_16x16x32_bf16(a0, b0, acc[0][0], 0, 0, 0);
            acc[0][1] = __builtin_amdgcn_mfma_f32_16x16x32_bf16(a1, b0, acc[0][1], 0, 0, 0);
            acc[0][2] = __builtin_amdgcn_mfma_f32_16x16x32_bf16(a2, b0, acc[0][2], 0, 0, 0);
            acc[0][3] = __builtin_amdgcn_mfma_f32_16x16x32_bf16(a3, b0, acc[0][3], 0, 0, 0);
            acc[1][0] = __builtin_amdgcn_mfma_f32_16x16x32_bf16(a0, b1, acc[1][0], 0, 0, 0);
            acc[1][1] = __builtin_amdgcn_mfma_f32_16x16x32_bf16(a1, b1, acc[1][1], 0, 0, 0);
            acc[1][2] = __builtin_amdgcn_mfma_f32_16x16x32_bf16(a2, b1, acc[1][2], 0, 0, 0);
            acc[1][3] = __builtin_amdgcn_mfma_f32_16x16x32_bf16(a3, b1, acc[1][3], 0, 0, 0);
        }
    }
    float bo0 = bout[vbw * 16 + (lane & 15)];
    float bo1 = bout[(vbw + 1) * 16 + (lane & 15)];
    int colb = vbw * 16 + (lane & 15);
    int g = lane >> 4;
#pragma unroll
    for (int mbi = 0; mbi < 4; ++mbi) {
#pragma unroll
        for (int r = 0; r < 4; ++r) {
            int row = mbi * 16 + g * 4 + r;      // C/D: row=(l>>4)*4+reg, col=l&15 (m89)
            float v1 = acc[0][mbi][r] + bo0; int i1 = colb;
            float v2 = acc[1][mbi][r] + bo1; int i2 = colb + 16;
            if (v2 > v1 || (v2 == v1 && i2 < i1)) {
                float tv = v1; int ti = i1; v1 = v2; i1 = i2; v2 = tv; i2 = ti;
            }
            for (int m = 1; m < 16; m <<= 1) {
                float ov1 = __shfl_xor(v1, m, 64); int oi1 = __shfl_xor(i1, m, 64);
                float ov2 = __shfl_xor(v2, m, 64); int oi2 = __shfl_xor(i2, m, 64);
                top2_merge(v1, i1, v2, i2, ov1, oi1, ov2, oi2);
            }
            if ((lane & 15) == 0) {
                sv1[w * 64 + row] = v1; si1[w * 64 + row] = i1;
                sv2[w * 64 + row] = v2; si2[w * 64 + row] = i2;
            }
        }
    }
    __syncthreads();
    if (tid < 64) {
        float v1 = sv1[tid]; int i1 = si1[tid];
        float v2 = sv2[tid]; int i2 = si2[tid];
        for (int q = 1; q < 4; ++q)
            top2_merge(v1, i1, v2, i2, sv1[q * 64 + tid], si1[q * 64 + tid],
                       sv2[q * 64 + tid], si2[q * 64 + tid]);
        pval[(size_t)tid * NC2 + tile * 2 + 0] = v1;
        pval[(size_t)tid * NC2 + tile * 2 + 1] = v2;
        pidx[(size_t)tid * NC2 + tile * 2 + 0] = i1;
        pidx[(size_t)tid * NC2 + tile * 2 + 1] = i2;
    }
}

// argmax: n in 0..63, wave 0 only
__device__ __forceinline__ void do_argmax(int n, int tid, int t,
        const float* __restrict__ pval, const int* __restrict__ pidx,
        const float* __restrict__ h_ws, const float* __restrict__ Wout,
        const float* __restrict__ bout, int* __restrict__ tok_ws, int* __restrict__ out) {
    if (tid >= 64) return;
    int lane = tid;
    const float* pv = pval + (size_t)n * NC2;
    const int*   pi = pidx + (size_t)n * NC2;
    float cv[8]; int ci[8];
#pragma unroll
    for (int q = 0; q < 8; ++q) {
        int i = q * 64 + lane;
        bool ok = i < NC2;
        cv[q] = ok ? pv[i] : -INFINITY;
        ci[q] = ok ? pi[i] : 0x7fffffff;
    }
    int picks[4];
#pragma unroll
    for (int c = 0; c < 4; ++c) {
        float best = -INFINITY; int bi = 0x7fffffff;
#pragma unroll
        for (int q = 0; q < 8; ++q) {
            bool skip = false;
#pragma unroll
            for (int p = 0; p < 4; ++p) skip = skip || (p < c && ci[q] == picks[p]);
            if (!skip && (cv[q] > best || (cv[q] == best && ci[q] < bi))) { best = cv[q]; bi = ci[q]; }
        }
        for (int m = 1; m < 64; m <<= 1) {
            float ov = __shfl_xor(best, m, 64);
            int   oi = __shfl_xor(bi, m, 64);
            if (ov > best || (ov == best && oi < bi)) { best = ov; bi = oi; }
        }
        picks[c] = bi;
    }
    const float* hr = h_ws + (size_t)n * HD;
    float hv[8];
#pragma unroll
    for (int j = 0; j < 8; ++j) hv[j] = hr[lane * 8 + j];
    float s0 = 0.f, s1 = 0.f, s2 = 0.f, s3 = 0.f;
#pragma unroll
    for (int j = 0; j < 8; ++j) {
        size_t krow = (size_t)(lane * 8 + j) * VD;
        s0 = fmaf(hv[j], Wout[krow + picks[0]], s0);
        s1 = fmaf(hv[j], Wout[krow + picks[1]], s1);
        s2 = fmaf(hv[j], Wout[krow + picks[2]], s2);
        s3 = fmaf(hv[j], Wout[krow + picks[3]], s3);
    }
    for (int m = 1; m < 64; m <<= 1) {
        s0 += __shfl_xor(s0, m, 64);
        s1 += __shfl_xor(s1, m, 64);
        s2 += __shfl_xor(s2, m, 64);
        s3 += __shfl_xor(s3, m, 64);
    }
    if (lane == 0) {
        float pex[4] = {s0 + bout[picks[0]], s1 + bout[picks[1]],
                        s2 + bout[picks[2]], s3 + bout[picks[3]]};
        float best = pex[0]; int bi = picks[0];
        for (int c = 1; c < 4; ++c)
            if (pex[c] > best || (pex[c] == best && picks[c] < bi)) { best = pex[c]; bi = picks[c]; }
        tok_ws[n] = bi;
        out[n * TS + t] = bi;
    }
}

// ================= persistent mega-kernel: all 20 steps, software grid barrier =========
__global__ void __launch_bounds__(256)
k_steps(const float* hl, const float* emb, const float* Ua, const float* ba,
        const float* va, const float* Wb, const float* bb, const float* Wx,
        const float* Wh, const float* b_lstm, const float* Wout, const float* bout,
        const unsigned short* WoutB, const float* hlwa,
        float* h_ws, float* c_ws, float* z_ws, float* e_ws, int* tok_ws,
        float* hua_part, float* gates_part, float* pval, int* pidx,
        unsigned short* hB, int* out, unsigned* barcnt) {
    __shared__ __attribute__((aligned(16))) float smem[9472];   // 37 KB union
    int blk = blockIdx.x, tid = threadIdx.x;
    unsigned bar_target = 0;
#define GSYNC() do { bar_target += NBLK; gridbar(barcnt, bar_target); } while (0)

    // prologue: attention pipeline for t=0
    if (blk < 64) do_hua(blk, tid, smem, h_ws, Ua, hua_part);
    GSYNC();
    if (blk < 192) do_att_e(blk, tid, hlwa, hua_part, ba, va, e_ws);
    GSYNC();
    if (blk < 64) do_soft_z(blk, tid, smem, e_ws, hl, h_ws, Wb, bb, z_ws);
    GSYNC();

    for (int t = 0; t < TS; ++t) {
        // A: gates(t)  [z(t), tok(t), h(t)]
        do_gates(blk, tid, smem, z_ws, emb, tok_ws, h_ws, Wx, Wh, gates_part);
        GSYNC();
        // B: lstm(t) -> h(t+1), c, hB
        if (blk < 128) do_lstm(blk, tid, gates_part, b_lstm, h_ws, c_ws, hB);
        GSYNC();
        // C: logits(t) on blocks 0..191 (235 tiles)  ||  hua(t+1) on blocks 192..255
        if (blk < 192) {
            do_logits(blk, tid, smem, hB, WoutB, bout, pval, pidx);
            if (blk < NBL - 192) do_logits(blk + 192, tid, smem, hB, WoutB, bout, pval, pidx);
        } else if (t < TS - 1) {
            do_hua(blk - 192, tid, smem, h_ws, Ua, hua_part);
        }
        GSYNC();
        // D: argmax(t) -> tok(t+1), out  ||  att_e(t+1)
        if (blk < 64) do_argmax(blk, tid, t, pval, pidx, h_ws, Wout, bout, tok_ws, out);
        else if (t < TS - 1) do_att_e(blk - 64, tid, hlwa, hua_part, ba, va, e_ws);
        GSYNC();
        // E: soft_z(t+1)
        if (blk < 64 && t < TS - 1)
            do_soft_z(blk, tid, smem, e_ws, hl, h_ws, Wb, bb, z_ws);
        GSYNC();
    }
#undef GSYNC
}

extern "C" void kernel_launch(void* const* d_in, const int* in_sizes, int n_in,
                              void* d_out, int out_size, void* d_ws, size_t ws_size,
                              hipStream_t stream) {
    const float* hl     = (const float*)d_in[0];
    const float* emb    = (const float*)d_in[1];
    const float* Wh0    = (const float*)d_in[2];
    const float* bh0    = (const float*)d_in[3];
    const float* Wc0    = (const float*)d_in[4];
    const float* bc0    = (const float*)d_in[5];
    const float* Wa     = (const float*)d_in[6];
    const float* Ua     = (const float*)d_in[7];
    const float* ba     = (const float*)d_in[8];
    const float* va     = (const float*)d_in[9];
    const float* Wb     = (const float*)d_in[10];
    const float* bb     = (const float*)d_in[11];
    const float* Wx     = (const float*)d_in[12];
    const float* Wh     = (const float*)d_in[13];
    const float* b_lstm = (const float*)d_in[14];
    const float* Wout   = (const float*)d_in[15];
    const float* bout   = (const float*)d_in[16];

    float* ws         = (float*)d_ws;
    float* hlwa       = ws;                          // 6422528
    float* h_ws       = ws + 6422528;                // 32768
    float* c_ws       = h_ws + 32768;                // 32768
    float* z_ws       = c_ws + 32768;                // 32768
    float* e_ws       = z_ws + 32768;                // 12544
    int*   tok_ws     = (int*)(e_ws + 12544);        // 64
    float* hua_part   = e_ws + 12544 + 64;           // 8*64*512 = 262144
    float* gates_part = hua_part + 262144;           // 8*64*2048 = 1048576
    float* pval       = gates_part + 1048576;        // 64*470 = 30080
    int*   pidx       = (int*)(pval + 64 * NC2);     // 30080
    unsigned short* hB    = (unsigned short*)(pval + 2 * 64 * NC2);          // 32768 u16
    unsigned short* WoutB = (unsigned short*)(pval + 2 * 64 * NC2 + 16384);  // 15.36M u16
    unsigned* barcnt  = (unsigned*)(ws + 15600704);  // after WoutB (7680000 floats)
    int*   out        = (int*)d_out;

    k_init<<<64, 256, 0, stream>>>(hl, Wh0, bh0, Wc0, bc0, h_ws, c_ws, tok_ws, barcnt);
    k_wcvt<<<7500, 256, 0, stream>>>(Wout, WoutB);
    k_hlwa<<<dim3(196, 8), 256, 0, stream>>>(hl, Wa, hlwa);
    k_steps<<<NBLK, 256, 0, stream>>>(hl, emb, Ua, ba, va, Wb, bb, Wx, Wh, b_lstm,
                                      Wout, bout, WoutB, hlwa, h_ws, c_ws, z_ws, e_ws,
                                      tok_ws, hua_part, gates_part, pval, pidx, hB, out,
                                      barcnt);
}

// Round 6
// 4312.689 us; speedup vs baseline: 1.9200x; 1.9200x over previous
//
#include <hip/hip_runtime.h>
#include <math.h>

#define NB   64      // batch
#define LL   196     // regions
#define AD   512     // image feat dim
#define HD   512     // hidden
#define VD   30000   // vocab
#define TS   20      // steps
#define G4   2048    // 4*H
#define NBL  235     // ceil(30000/128) logits tiles
#define NC2  (NBL * 2)   // top-2 candidates per tile per row = 470
#define NBLK 256     // persistent grid size

typedef __bf16 bf16x8 __attribute__((ext_vector_type(8)));
typedef float  f32x4  __attribute__((ext_vector_type(4)));

__device__ __forceinline__ float fast_tanh(float x) {
    float e = __builtin_exp2f(x * 2.8853900817779268f);   // exp(2x)
    return 1.0f - 2.0f / (e + 1.0f);
}
__device__ __forceinline__ float fast_sigmoid(float x) {
    return 1.0f / (1.0f + __builtin_exp2f(-x * 1.4426950408889634f));
}
__device__ __forceinline__ float fast_exp(float x) {
    return __builtin_exp2f(x * 1.4426950408889634f);
}
__device__ __forceinline__ unsigned short f2bf(float f) {   // RNE fp32->bf16
    unsigned int u = __float_as_uint(f);
    u += 0x7fffu + ((u >> 16) & 1u);
    return (unsigned short)(u >> 16);
}
// async global->LDS DMA, 16B per lane; lds base must be wave-uniform
__device__ __forceinline__ void gload_lds16(const void* g, void* l) {
    __builtin_amdgcn_global_load_lds((const __attribute__((address_space(1))) void*)g,
                                     (__attribute__((address_space(3))) void*)l, 16, 0, 0);
}
// merge two (top1, top2) candidate pairs, tie-break: smaller index wins
__device__ __forceinline__ void top2_merge(float& v1, int& i1, float& v2, int& i2,
                                           float ov1, int oi1, float ov2, int oi2) {
    if (ov1 > v1 || (ov1 == v1 && oi1 < i1)) {
        float sv = v1; int si = i1;
        v1 = ov1; i1 = oi1;
        if (ov2 > sv || (ov2 == sv && oi2 < si)) { v2 = ov2; i2 = oi2; }
        else { v2 = sv; i2 = si; }
    } else {
        if (ov1 > v2 || (ov1 == v2 && oi1 < i2)) { v2 = ov1; i2 = oi1; }
    }
}

// device-scope grid barrier, v2.
// Round-5 bug: ACQUIRE spin-load invalidated per-XCD L2 on EVERY poll iteration
// (256 pollers x ~128cy = continuous L2 nuke storm -> 181 GB/s effective, 78us/barrier).
// v2: release-RMW arrive (one wbl2), RELAXED polls (agent atomics hit the coherence
// point without invalidating caches), ONE acquire fence after the spin exits.
__device__ __forceinline__ void gridbar(unsigned* cnt, unsigned target) {
    __syncthreads();
    if (threadIdx.x == 0) {
        __hip_atomic_fetch_add(cnt, 1u, __ATOMIC_RELEASE, __HIP_MEMORY_SCOPE_AGENT);
        while (__hip_atomic_load(cnt, __ATOMIC_RELAXED, __HIP_MEMORY_SCOPE_AGENT) < target) {
            __builtin_amdgcn_s_sleep(2);
        }
        __builtin_amdgcn_fence(__ATOMIC_ACQUIRE, "agent");   // one L1+L2 inv per barrier
    }
    __syncthreads();
}

// ---------------- precompute: mean over L, h0/c0, tok init, barrier reset ----------------
__global__ void k_init(const float* __restrict__ hl, const float* __restrict__ Wh0,
                       const float* __restrict__ bh0, const float* __restrict__ Wc0,
                       const float* __restrict__ bc0, float* __restrict__ h_ws,
                       float* __restrict__ c_ws, int* __restrict__ tok_ws,
                       unsigned* __restrict__ barcnt) {
    __shared__ float mean_s[AD];
    int n = blockIdx.x, tid = threadIdx.x;
    if (n == 0 && tid == 0) *barcnt = 0u;   // replay-safe barrier reset
    for (int a = tid; a < AD; a += 256) {
        float acc = 0.f;
        const float* p = hl + ((size_t)n * LL) * AD + a;
        for (int l = 0; l < LL; ++l) acc += p[(size_t)l * AD];
        mean_s[a] = acc / 196.0f;
    }
    __syncthreads();
    for (int hh = tid; hh < HD; hh += 256) {
        float ah = bh0[hh], ac = bc0[hh];
        for (int k = 0; k < AD; ++k) {
            float m = mean_s[k];
            ah = fmaf(m, Wh0[k * HD + hh], ah);
            ac = fmaf(m, Wc0[k * HD + hh], ac);
        }
        h_ws[n * HD + hh] = fast_tanh(ah);
        c_ws[n * HD + hh] = fast_tanh(ac);
    }
    if (tid == 0) tok_ws[n] = 1;  // START
}

// ---------------- precompute: hl_Wa = hl @ Wa  (12544x512 @ 512x512) ----------------
__global__ void k_hlwa(const float* __restrict__ Amat, const float* __restrict__ Bmat,
                       float* __restrict__ Cmat) {
    __shared__ __attribute__((aligned(16))) float xt[64 * 64];  // (k, m) skewed
    __shared__ __attribute__((aligned(16))) float bs[64 * 68];  // (k, j) stride-68
    int tid = threadIdx.x;
    int lane16 = tid & 15, rowg = tid >> 4;
    int m0 = blockIdx.x * 64, jb = blockIdx.y * 64;
    float acc[4][4] = {};
    for (int ch = 0; ch < 8; ++ch) {
        int kbase = ch * 64;
        __syncthreads();
        for (int it = 0; it < 4; ++it) {
            int k4 = tid & 15;
            int nrow = (tid >> 4) + it * 16;
            float4 v = *(const float4*)&Amat[(size_t)(m0 + nrow) * 512 + kbase + k4 * 4];
            int col = (nrow + k4 * 4) & 63;
            xt[(k4 * 4 + 0) * 64 + col] = v.x;
            xt[(k4 * 4 + 1) * 64 + col] = v.y;
            xt[(k4 * 4 + 2) * 64 + col] = v.z;
            xt[(k4 * 4 + 3) * 64 + col] = v.w;
        }
        for (int it = 0; it < 4; ++it) {
            int r = it * 16 + (tid >> 4);
            int c4 = (tid & 15) * 4;
            *(float4*)&bs[r * 68 + c4] = *(const float4*)&Bmat[(size_t)(kbase + r) * 512 + jb + c4];
        }
        __syncthreads();
#pragma unroll 8
        for (int kk = 0; kk < 64; ++kk) {
            float4 w4 = *(const float4*)&bs[kk * 68 + lane16 * 4];
            float4 h4 = *(const float4*)&xt[kk * 64 + ((rowg * 4 + (kk & ~3)) & 63)];
            float hv[4] = {h4.x, h4.y, h4.z, h4.w};
            float wv[4] = {w4.x, w4.y, w4.z, w4.w};
#pragma unroll
            for (int r = 0; r < 4; ++r)
#pragma unroll
                for (int j = 0; j < 4; ++j) acc[r][j] = fmaf(hv[r], wv[j], acc[r][j]);
        }
    }
    for (int r = 0; r < 4; ++r) {
        float4 o = {acc[r][0], acc[r][1], acc[r][2], acc[r][3]};
        *(float4*)&Cmat[(size_t)(m0 + rowg * 4 + r) * 512 + jb + lane16 * 4] = o;
    }
}

// ---------------- one-shot: pack Wout (fp32 [512][30000]) -> bf16 B-fragments ----------
__global__ void k_wcvt(const float* __restrict__ Wout, unsigned short* __restrict__ WoutB) {
    int id = blockIdx.x * 256 + threadIdx.x;      // 0 .. 1,920,000-1
    int lane = id & 63;
    int kb = (id >> 6) & 15;
    int vb = id >> 10;
    int v  = vb * 16 + (lane & 15);
    int k0 = kb * 32 + (lane >> 4) * 8;
    unsigned int pk[4];
#pragma unroll
    for (int p = 0; p < 4; ++p) {
        unsigned int lo = f2bf(Wout[(size_t)(k0 + 2 * p) * VD + v]);
        unsigned int hi = f2bf(Wout[(size_t)(k0 + 2 * p + 1) * VD + v]);
        pk[p] = lo | (hi << 16);
    }
    *(uint4*)&WoutB[(size_t)id * 8] = make_uint4(pk[0], pk[1], pk[2], pk[3]);
}

// ================= device phase functions (math verbatim from verified kernels) =========

// hua: b in 0..63
__device__ __forceinline__ void do_hua(int b, int tid, float* smem,
        const float* __restrict__ h_ws, const float* __restrict__ Ua,
        float* __restrict__ hua_part) {
    float* xt = smem;          // 4096 floats
    float* us = smem + 4096;   // 4352 floats
    int lane16 = tid & 15, rowg = tid >> 4;
    int s = b & 7, jt = b >> 3;
    int jb = jt * 64, kbase = s * 64;
    float acc[4][4] = {};
    for (int it = 0; it < 4; ++it) {
        int k4 = tid & 15;
        int nrow = (tid >> 4) + it * 16;
        float4 v = *(const float4*)&h_ws[nrow * 512 + kbase + k4 * 4];
        int col = (nrow + k4 * 4) & 63;
        xt[(k4 * 4 + 0) * 64 + col] = v.x;
        xt[(k4 * 4 + 1) * 64 + col] = v.y;
        xt[(k4 * 4 + 2) * 64 + col] = v.z;
        xt[(k4 * 4 + 3) * 64 + col] = v.w;
    }
    for (int it = 0; it < 4; ++it) {
        int r = it * 16 + (tid >> 4);
        int c4 = (tid & 15) * 4;
        *(float4*)&us[r * 68 + c4] = *(const float4*)&Ua[(size_t)(kbase + r) * 512 + jb + c4];
    }
    __syncthreads();
#pragma unroll 8
    for (int kk = 0; kk < 64; ++kk) {
        float4 w4 = *(const float4*)&us[kk * 68 + lane16 * 4];
        float4 h4 = *(const float4*)&xt[kk * 64 + ((rowg * 4 + (kk & ~3)) & 63)];
        float hv[4] = {h4.x, h4.y, h4.z, h4.w};
        float wv[4] = {w4.x, w4.y, w4.z, w4.w};
#pragma unroll
        for (int r = 0; r < 4; ++r)
#pragma unroll
            for (int j = 0; j < 4; ++j) acc[r][j] = fmaf(hv[r], wv[j], acc[r][j]);
    }
    float* gp = hua_part + (size_t)s * NB * HD;
    for (int r = 0; r < 4; ++r) {
        float4 o = {acc[r][0], acc[r][1], acc[r][2], acc[r][3]};
        *(float4*)&gp[(size_t)(rowg * 4 + r) * 512 + jb + lane16 * 4] = o;
    }
}

// att_e: b in 0..191 -> n = b&63, q = b>>6 (3-way row split; per-l math identical)
__device__ __forceinline__ void do_att_e(int b, int tid,
        const float* __restrict__ hlwa, const float* __restrict__ hua_part,
        const float* __restrict__ ba, const float* __restrict__ va,
        float* __restrict__ e_ws) {
    int n = b & 63, q = b >> 6;
    int wave = tid >> 6, lane = tid & 63;
    float4 ua_a = *(const float4*)&ba[lane * 4];
    float4 ua_b = *(const float4*)&ba[256 + lane * 4];
    for (int s = 0; s < 8; ++s) {
        const float* p = hua_part + (size_t)s * NB * HD + n * HD;
        float4 pa = *(const float4*)&p[lane * 4];
        float4 pb = *(const float4*)&p[256 + lane * 4];
        ua_a.x += pa.x; ua_a.y += pa.y; ua_a.z += pa.z; ua_a.w += pa.w;
        ua_b.x += pb.x; ua_b.y += pb.y; ua_b.z += pb.z; ua_b.w += pb.w;
    }
    float4 va_a = *(const float4*)&va[lane * 4];
    float4 va_b = *(const float4*)&va[256 + lane * 4];
    int lstart = q * 66, lend = (q == 2) ? LL : (q * 66 + 66);
    for (int l = lstart + wave; l < lend; l += 4) {
        const float* base = hlwa + ((size_t)n * LL + l) * HD;
        float4 xa = *(const float4*)&base[lane * 4];
        float4 xb = *(const float4*)&base[256 + lane * 4];
        float s = 0.f;
        s = fmaf(fast_tanh(xa.x + ua_a.x), va_a.x, s);
        s = fmaf(fast_tanh(xa.y + ua_a.y), va_a.y, s);
        s = fmaf(fast_tanh(xa.z + ua_a.z), va_a.z, s);
        s = fmaf(fast_tanh(xa.w + ua_a.w), va_a.w, s);
        s = fmaf(fast_tanh(xb.x + ua_b.x), va_b.x, s);
        s = fmaf(fast_tanh(xb.y + ua_b.y), va_b.y, s);
        s = fmaf(fast_tanh(xb.z + ua_b.z), va_b.z, s);
        s = fmaf(fast_tanh(xb.w + ua_b.w), va_b.w, s);
        for (int m = 1; m < 64; m <<= 1) s += __shfl_xor(s, m, 64);
        if (lane == 0) e_ws[n * LL + l] = s;
    }
}

// soft_z: n in 0..63
__device__ __forceinline__ void do_soft_z(int n, int tid, float* smem,
        const float* __restrict__ e_ws, const float* __restrict__ hl,
        const float* __restrict__ h_ws, const float* __restrict__ Wb,
        const float* __restrict__ bb, float* __restrict__ z_ws) {
    float* red = smem;            // 256
    float* alpha = smem + 256;    // 256
    float* zs = smem + 512;       // 512
    // beta at smem[1024]
    float ev = (tid < LL) ? e_ws[n * LL + tid] : -INFINITY;
    red[tid] = ev;
    __syncthreads();
    for (int s = 128; s > 0; s >>= 1) {
        if (tid < s) red[tid] = fmaxf(red[tid], red[tid + s]);
        __syncthreads();
    }
    float m = red[0];
    __syncthreads();
    float a = (tid < LL) ? fast_exp(ev - m) : 0.f;
    red[tid] = a;
    __syncthreads();
    for (int s = 128; s > 0; s >>= 1) {
        if (tid < s) red[tid] += red[tid + s];
        __syncthreads();
    }
    float sum = red[0];
    alpha[tid] = a / sum;
    __syncthreads();
    float bp = h_ws[n * HD + tid] * Wb[tid] + h_ws[n * HD + 256 + tid] * Wb[256 + tid];
    red[tid] = bp;
    __syncthreads();
    for (int s = 128; s > 0; s >>= 1) {
        if (tid < s) red[tid] += red[tid + s];
        __syncthreads();
    }
    if (tid == 0) smem[1024] = fast_sigmoid(red[0] + bb[0]);
    int lq = tid >> 7, ai = tid & 127;
    const float* base = hl + ((size_t)n * LL) * AD + ai * 4;
    float4 acc4 = {0.f, 0.f, 0.f, 0.f};
    int l0 = lq * 98, l1 = l0 + 98;
    for (int l = l0; l < l1; ++l) {
        float al = alpha[l];
        float4 v = *(const float4*)&base[(size_t)l * AD];
        acc4.x = fmaf(al, v.x, acc4.x);
        acc4.y = fmaf(al, v.y, acc4.y);
        acc4.z = fmaf(al, v.z, acc4.z);
        acc4.w = fmaf(al, v.w, acc4.w);
    }
    if (lq == 1) *(float4*)&zs[ai * 4] = acc4;
    __syncthreads();
    if (lq == 0) {
        float4 o = *(const float4*)&zs[ai * 4];
        float b = smem[1024];
        o.x = (o.x + acc4.x) * b;
        o.y = (o.y + acc4.y) * b;
        o.z = (o.z + acc4.z) * b;
        o.w = (o.w + acc4.w) * b;
        *(float4*)&z_ws[n * AD + ai * 4] = o;
    }
}

// gates: b in 0..255
__device__ __forceinline__ void do_gates(int b, int tid, float* smem,
        const float* __restrict__ z_ws, const float* __restrict__ emb,
        const int* __restrict__ tok_ws, const float* __restrict__ h_ws,
        const float* __restrict__ Wx, const float* __restrict__ Wh,
        float* __restrict__ gates_part) {
    float* xt = smem;          // 4096
    float* wsl = smem + 4096;  // 4352
    int lane16 = tid & 15, rowg = tid >> 4;
    int s = b & 7, jt = b >> 3;
    int jb = jt * 64;
    float acc[4][4] = {};
    for (int ch = 0; ch < 3; ++ch) {
        int kbase = s * 192 + ch * 64;
        __syncthreads();
        for (int it = 0; it < 4; ++it) {
            int nrow = (tid >> 4) + it * 16;
            int k4 = tid & 15;
            int gk = kbase + k4 * 4;
            const float* src;
            if (gk < 512)       src = &z_ws[nrow * 512 + gk];
            else if (gk < 1024) src = &emb[(size_t)tok_ws[nrow] * 512 + (gk - 512)];
            else                src = &h_ws[nrow * 512 + (gk - 1024)];
            float4 v = *(const float4*)src;
            int col = (nrow + k4 * 4) & 63;
            xt[(k4 * 4 + 0) * 64 + col] = v.x;
            xt[(k4 * 4 + 1) * 64 + col] = v.y;
            xt[(k4 * 4 + 2) * 64 + col] = v.z;
            xt[(k4 * 4 + 3) * 64 + col] = v.w;
        }
        for (int it = 0; it < 4; ++it) {
            int r = it * 16 + (tid >> 4);
            int gk = kbase + r;
            const float* wrow = (gk < 1024) ? &Wx[(size_t)gk * G4] : &Wh[(size_t)(gk - 1024) * G4];
            int c4 = (tid & 15) * 4;
            *(float4*)&wsl[r * 68 + c4] = *(const float4*)&wrow[jb + c4];
        }
        __syncthreads();
#pragma unroll 8
        for (int kk = 0; kk < 64; ++kk) {
            float4 w4 = *(const float4*)&wsl[kk * 68 + lane16 * 4];
            float4 h4 = *(const float4*)&xt[kk * 64 + ((rowg * 4 + (kk & ~3)) & 63)];
            float hv[4] = {h4.x, h4.y, h4.z, h4.w};
            float wv[4] = {w4.x, w4.y, w4.z, w4.w};
#pragma unroll
            for (int r = 0; r < 4; ++r)
#pragma unroll
                for (int j = 0; j < 4; ++j) acc[r][j] = fmaf(hv[r], wv[j], acc[r][j]);
        }
    }
    float* gp = gates_part + (size_t)s * NB * G4;
    for (int r = 0; r < 4; ++r) {
        float4 o = {acc[r][0], acc[r][1], acc[r][2], acc[r][3]};
        *(float4*)&gp[(size_t)(rowg * 4 + r) * G4 + jb + lane16 * 4] = o;
    }
}

// lstm: b in 0..127
__device__ __forceinline__ void do_lstm(int b, int tid,
        const float* __restrict__ gates_part, const float* __restrict__ b_lstm,
        float* __restrict__ h_ws, float* __restrict__ c_ws,
        unsigned short* __restrict__ hB) {
    int idx = b * 256 + tid;  // 0..32767
    int n = idx >> 9, hh = idx & 511;
    float ig = b_lstm[hh], fg = b_lstm[512 + hh], gg = b_lstm[1024 + hh], og = b_lstm[1536 + hh];
    for (int s = 0; s < 8; ++s) {
        const float* gp = gates_part + (size_t)s * NB * G4 + (size_t)n * G4;
        ig += gp[hh]; fg += gp[512 + hh]; gg += gp[1024 + hh]; og += gp[1536 + hh];
    }
    float c = c_ws[idx];
    float cn = fast_sigmoid(fg) * c + fast_sigmoid(ig) * fast_tanh(gg);
    float hn = fast_sigmoid(og) * fast_tanh(cn);
    c_ws[idx] = cn;
    h_ws[idx] = hn;
    int mb = n >> 4, kb = hh >> 5;
    int lane = (n & 15) + ((hh >> 3) & 3) * 16;
    hB[(((size_t)mb * 16 + kb) * 64 + lane) * 8 + (hh & 7)] = f2bf(hn);
}

// logits: one 128-col vocab tile (0..234); hB staged in two 32KB LDS halves
__device__ __forceinline__ void do_logits(int tile, int tid, float* smem,
        const unsigned short* __restrict__ hB, const unsigned short* __restrict__ WoutB,
        const float* __restrict__ bout, float* __restrict__ pval, int* __restrict__ pidx) {
    unsigned short* hs = (unsigned short*)smem;   // 32 KB = 2048 16B-slots
    float* sv1 = smem + 8192; float* sv2 = smem + 8448;
    int* si1 = (int*)(smem + 8704); int* si2 = (int*)(smem + 8960);
    int w = tid >> 6, lane = tid & 63;
    int jb = tile * 128;
    if (jb > VD - 128) jb = VD - 128;
    int vbw = (jb >> 4) + w * 2;
    const bf16x8* wP = (const bf16x8*)WoutB;
    const bf16x8* hP = (const bf16x8*)hs;
    f32x4 acc[2][4] = {};
    for (int hf = 0; hf < 2; ++hf) {
        __syncthreads();   // prior hs/sv use complete before restage
#pragma unroll
        for (int i = 0; i < 8; ++i) {
            int sbase = i * 256 + w * 64;
            int mb = sbase >> 9, kb2 = (sbase >> 6) & 7;
            int gslot = (mb * 16 + hf * 8 + kb2) * 64;
            gload_lds16(&hB[(size_t)(gslot + lane) * 8], &hs[(size_t)sbase * 8]);
        }
        __syncthreads();   // drains DMA
#pragma unroll 2
        for (int kb2 = 0; kb2 < 8; ++kb2) {
            int kb = hf * 8 + kb2;
            bf16x8 b0 = wP[((size_t)vbw * 16 + kb) * 64 + lane];
            bf16x8 b1 = wP[((size_t)(vbw + 1) * 16 + kb) * 64 + lane];
            bf16x8 a0 = hP[(0 * 8 + kb2) * 64 + lane];
            bf16x8 a1 = hP[(1 * 8 + kb2) * 64 + lane];
            bf16x8 a2 = hP[(2 * 8 + kb2) * 64 + lane];
            bf16x8 a3 = hP[(3 * 8 + kb2) * 64 + lane];
            acc[0][0] = __builtin_amdgcn_mfma_f32_16x16x32_bf16(a0, b0, acc[0][0], 0, 0, 0);
            acc[0][1] = __builtin_amdgcn_mfma_f32_16x16x32_bf16(a1, b0, acc[0][1], 0, 0, 0);
            acc[0][2] = __builtin_amdgcn_mfma_f32_16x16x32_bf16(a2, b0, acc[0][2], 0, 0, 0);
            acc[0][3] = __builtin_amdgcn_mfma_f32_16x16x32_bf16(a3, b0, acc[0][3], 0, 0, 0);
            acc[1][0] = __builtin_amdgcn_mfma_f32_16x16x32_bf16(a0, b1, acc[1][0], 0, 0, 0);
            acc[1][1] = __builtin_amdgcn_mfma_f32_16x16x32_bf16(a1, b1, acc[1][1], 0, 0, 0);
            acc[1][2] = __builtin_amdgcn_mfma_f32_16x16x32_bf16(a2, b1, acc[1][2], 0, 0, 0);
            acc[1][3] = __builtin_amdgcn_mfma_f32_16x16x32_bf16(a3, b1, acc[1][3], 0, 0, 0);
        }
    }
    float bo0 = bout[vbw * 16 + (lane & 15)];
    float bo1 = bout[(vbw + 1) * 16 + (lane & 15)];
    int colb = vbw * 16 + (lane & 15);
    int g = lane >> 4;
#pragma unroll
    for (int mbi = 0; mbi < 4; ++mbi) {
#pragma unroll
        for (int r = 0; r < 4; ++r) {
            int row = mbi * 16 + g * 4 + r;      // C/D: row=(l>>4)*4+reg, col=l&15 (m89)
            float v1 = acc[0][mbi][r] + bo0; int i1 = colb;
            float v2 = acc[1][mbi][r] + bo1; int i2 = colb + 16;
            if (v2 > v1 || (v2 == v1 && i2 < i1)) {
                float tv = v1; int ti = i1; v1 = v2; i1 = i2; v2 = tv; i2 = ti;
            }
            for (int m = 1; m < 16; m <<= 1) {
                float ov1 = __shfl_xor(v1, m, 64); int oi1 = __shfl_xor(i1, m, 64);
                float ov2 = __shfl_xor(v2, m, 64); int oi2 = __shfl_xor(i2, m, 64);
                top2_merge(v1, i1, v2, i2, ov1, oi1, ov2, oi2);
            }
            if ((lane & 15) == 0) {
                sv1[w * 64 + row] = v1; si1[w * 64 + row] = i1;
                sv2[w * 64 + row] = v2; si2[w * 64 + row] = i2;
            }
        }
    }
    __syncthreads();
    if (tid < 64) {
        float v1 = sv1[tid]; int i1 = si1[tid];
        float v2 = sv2[tid]; int i2 = si2[tid];
        for (int q = 1; q < 4; ++q)
            top2_merge(v1, i1, v2, i2, sv1[q * 64 + tid], si1[q * 64 + tid],
                       sv2[q * 64 + tid], si2[q * 64 + tid]);
        pval[(size_t)tid * NC2 + tile * 2 + 0] = v1;
        pval[(size_t)tid * NC2 + tile * 2 + 1] = v2;
        pidx[(size_t)tid * NC2 + tile * 2 + 0] = i1;
        pidx[(size_t)tid * NC2 + tile * 2 + 1] = i2;
    }
}

// argmax: n in 0..63, wave 0 only
__device__ __forceinline__ void do_argmax(int n, int tid, int t,
        const float* __restrict__ pval, const int* __restrict__ pidx,
        const float* __restrict__ h_ws, const float* __restrict__ Wout,
        const float* __restrict__ bout, int* __restrict__ tok_ws, int* __restrict__ out) {
    if (tid >= 64) return;
    int lane = tid;
    const float* pv = pval + (size_t)n * NC2;
    const int*   pi = pidx + (size_t)n * NC2;
    float cv[8]; int ci[8];
#pragma unroll
    for (int q = 0; q < 8; ++q) {
        int i = q * 64 + lane;
        bool ok = i < NC2;
        cv[q] = ok ? pv[i] : -INFINITY;
        ci[q] = ok ? pi[i] : 0x7fffffff;
    }
    int picks[4];
#pragma unroll
    for (int c = 0; c < 4; ++c) {
        float best = -INFINITY; int bi = 0x7fffffff;
#pragma unroll
        for (int q = 0; q < 8; ++q) {
            bool skip = false;
#pragma unroll
            for (int p = 0; p < 4; ++p) skip = skip || (p < c && ci[q] == picks[p]);
            if (!skip && (cv[q] > best || (cv[q] == best && ci[q] < bi))) { best = cv[q]; bi = ci[q]; }
        }
        for (int m = 1; m < 64; m <<= 1) {
            float ov = __shfl_xor(best, m, 64);
            int   oi = __shfl_xor(bi, m, 64);
            if (ov > best || (ov == best && oi < bi)) { best = ov; bi = oi; }
        }
        picks[c] = bi;
    }
    const float* hr = h_ws + (size_t)n * HD;
    float hv[8];
#pragma unroll
    for (int j = 0; j < 8; ++j) hv[j] = hr[lane * 8 + j];
    float s0 = 0.f, s1 = 0.f, s2 = 0.f, s3 = 0.f;
#pragma unroll
    for (int j = 0; j < 8; ++j) {
        size_t krow = (size_t)(lane * 8 + j) * VD;
        s0 = fmaf(hv[j], Wout[krow + picks[0]], s0);
        s1 = fmaf(hv[j], Wout[krow + picks[1]], s1);
        s2 = fmaf(hv[j], Wout[krow + picks[2]], s2);
        s3 = fmaf(hv[j], Wout[krow + picks[3]], s3);
    }
    for (int m = 1; m < 64; m <<= 1) {
        s0 += __shfl_xor(s0, m, 64);
        s1 += __shfl_xor(s1, m, 64);
        s2 += __shfl_xor(s2, m, 64);
        s3 += __shfl_xor(s3, m, 64);
    }
    if (lane == 0) {
        float pex[4] = {s0 + bout[picks[0]], s1 + bout[picks[1]],
                        s2 + bout[picks[2]], s3 + bout[picks[3]]};
        float best = pex[0]; int bi = picks[0];
        for (int c = 1; c < 4; ++c)
            if (pex[c] > best || (pex[c] == best && picks[c] < bi)) { best = pex[c]; bi = picks[c]; }
        tok_ws[n] = bi;
        out[n * TS + t] = bi;
    }
}

// ================= persistent mega-kernel: all 20 steps, software grid barrier =========
__global__ void __launch_bounds__(256)
k_steps(const float* hl, const float* emb, const float* Ua, const float* ba,
        const float* va, const float* Wb, const float* bb, const float* Wx,
        const float* Wh, const float* b_lstm, const float* Wout, const float* bout,
        const unsigned short* WoutB, const float* hlwa,
        float* h_ws, float* c_ws, float* z_ws, float* e_ws, int* tok_ws,
        float* hua_part, float* gates_part, float* pval, int* pidx,
        unsigned short* hB, int* out, unsigned* barcnt) {
    __shared__ __attribute__((aligned(16))) float smem[9472];   // 37 KB union
    int blk = blockIdx.x, tid = threadIdx.x;
    unsigned bar_target = 0;
#define GSYNC() do { bar_target += NBLK; gridbar(barcnt, bar_target); } while (0)

    // prologue: attention pipeline for t=0
    if (blk < 64) do_hua(blk, tid, smem, h_ws, Ua, hua_part);
    GSYNC();
    if (blk < 192) do_att_e(blk, tid, hlwa, hua_part, ba, va, e_ws);
    GSYNC();
    if (blk < 64) do_soft_z(blk, tid, smem, e_ws, hl, h_ws, Wb, bb, z_ws);
    GSYNC();

    for (int t = 0; t < TS; ++t) {
        // A: gates(t)  [z(t), tok(t), h(t)]
        do_gates(blk, tid, smem, z_ws, emb, tok_ws, h_ws, Wx, Wh, gates_part);
        GSYNC();
        // B: lstm(t) -> h(t+1), c, hB
        if (blk < 128) do_lstm(blk, tid, gates_part, b_lstm, h_ws, c_ws, hB);
        GSYNC();
        // C: logits(t) on blocks 0..191 (235 tiles)  ||  hua(t+1) on blocks 192..255
        if (blk < 192) {
            do_logits(blk, tid, smem, hB, WoutB, bout, pval, pidx);
            if (blk < NBL - 192) do_logits(blk + 192, tid, smem, hB, WoutB, bout, pval, pidx);
        } else if (t < TS - 1) {
            do_hua(blk - 192, tid, smem, h_ws, Ua, hua_part);
        }
        GSYNC();
        // D: argmax(t) -> tok(t+1), out  ||  att_e(t+1)
        if (blk < 64) do_argmax(blk, tid, t, pval, pidx, h_ws, Wout, bout, tok_ws, out);
        else if (t < TS - 1) do_att_e(blk - 64, tid, hlwa, hua_part, ba, va, e_ws);
        GSYNC();
        // E: soft_z(t+1)
        if (blk < 64 && t < TS - 1)
            do_soft_z(blk, tid, smem, e_ws, hl, h_ws, Wb, bb, z_ws);
        GSYNC();
    }
#undef GSYNC
}

extern "C" void kernel_launch(void* const* d_in, const int* in_sizes, int n_in,
                              void* d_out, int out_size, void* d_ws, size_t ws_size,
                              hipStream_t stream) {
    const float* hl     = (const float*)d_in[0];
    const float* emb    = (const float*)d_in[1];
    const float* Wh0    = (const float*)d_in[2];
    const float* bh0    = (const float*)d_in[3];
    const float* Wc0    = (const float*)d_in[4];
    const float* bc0    = (const float*)d_in[5];
    const float* Wa     = (const float*)d_in[6];
    const float* Ua     = (const float*)d_in[7];
    const float* ba     = (const float*)d_in[8];
    const float* va     = (const float*)d_in[9];
    const float* Wb     = (const float*)d_in[10];
    const float* bb     = (const float*)d_in[11];
    const float* Wx     = (const float*)d_in[12];
    const float* Wh     = (const float*)d_in[13];
    const float* b_lstm = (const float*)d_in[14];
    const float* Wout   = (const float*)d_in[15];
    const float* bout   = (const float*)d_in[16];

    float* ws         = (float*)d_ws;
    float* hlwa       = ws;                          // 6422528
    float* h_ws       = ws + 6422528;                // 32768
    float* c_ws       = h_ws + 32768;                // 32768
    float* z_ws       = c_ws + 32768;                // 32768
    float* e_ws       = z_ws + 32768;                // 12544
    int*   tok_ws     = (int*)(e_ws + 12544);        // 64
    float* hua_part   = e_ws + 12544 + 64;           // 8*64*512 = 262144
    float* gates_part = hua_part + 262144;           // 8*64*2048 = 1048576
    float* pval       = gates_part + 1048576;        // 64*470 = 30080
    int*   pidx       = (int*)(pval + 64 * NC2);     // 30080
    unsigned short* hB    = (unsigned short*)(pval + 2 * 64 * NC2);          // 32768 u16
    unsigned short* WoutB = (unsigned short*)(pval + 2 * 64 * NC2 + 16384);  // 15.36M u16
    unsigned* barcnt  = (unsigned*)(ws + 15600704);  // after WoutB (7680000 floats)
    int*   out        = (int*)d_out;

    k_init<<<64, 256, 0, stream>>>(hl, Wh0, bh0, Wc0, bc0, h_ws, c_ws, tok_ws, barcnt);
    k_wcvt<<<7500, 256, 0, stream>>>(Wout, WoutB);
    k_hlwa<<<dim3(196, 8), 256, 0, stream>>>(hl, Wa, hlwa);
    k_steps<<<NBLK, 256, 0, stream>>>(hl, emb, Ua, ba, va, Wb, bb, Wx, Wh, b_lstm,
                                      Wout, bout, WoutB, hlwa, h_ws, c_ws, z_ws, e_ws,
                                      tok_ws, hua_part, gates_part, pval, pidx, hB, out,
                                      barcnt);
}

// Round 7
// 3607.963 us; speedup vs baseline: 2.2951x; 1.1953x over previous
//
#include <hip/hip_runtime.h>
#include <math.h>

#define NB   64      // batch
#define LL   196     // regions
#define AD   512     // image feat dim
#define HD   512     // hidden
#define VD   30000   // vocab
#define TS   20      // steps
#define G4   2048    // 4*H
#define NBL  235     // ceil(30000/128) logits tiles
#define NC2  (NBL * 2)   // top-2 candidates per tile per row = 470
#define NBLK 256     // persistent grid size

typedef __bf16 bf16x8 __attribute__((ext_vector_type(8)));
typedef float  f32x4  __attribute__((ext_vector_type(4)));

__device__ __forceinline__ float fast_tanh(float x) {
    float e = __builtin_exp2f(x * 2.8853900817779268f);   // exp(2x)
    return 1.0f - 2.0f / (e + 1.0f);
}
__device__ __forceinline__ float fast_sigmoid(float x) {
    return 1.0f / (1.0f + __builtin_exp2f(-x * 1.4426950408889634f));
}
__device__ __forceinline__ float fast_exp(float x) {
    return __builtin_exp2f(x * 1.4426950408889634f);
}
__device__ __forceinline__ unsigned short f2bf(float f) {   // RNE fp32->bf16
    unsigned int u = __float_as_uint(f);
    u += 0x7fffu + ((u >> 16) & 1u);
    return (unsigned short)(u >> 16);
}
// async global->LDS DMA, 16B per lane; lds base must be wave-uniform
__device__ __forceinline__ void gload_lds16(const void* g, void* l) {
    __builtin_amdgcn_global_load_lds((const __attribute__((address_space(1))) void*)g,
                                     (__attribute__((address_space(3))) void*)l, 16, 0, 0);
}
// merge two (top1, top2) candidate pairs, tie-break: smaller index wins
__device__ __forceinline__ void top2_merge(float& v1, int& i1, float& v2, int& i2,
                                           float ov1, int oi1, float ov2, int oi2) {
    if (ov1 > v1 || (ov1 == v1 && oi1 < i1)) {
        float sv = v1; int si = i1;
        v1 = ov1; i1 = oi1;
        if (ov2 > sv || (ov2 == sv && oi2 < si)) { v2 = ov2; i2 = oi2; }
        else { v2 = sv; i2 = si; }
    } else {
        if (ov1 > v2 || (ov1 == v2 && oi1 < i2)) { v2 = ov1; i2 = oi1; }
    }
}

// distributed-flag grid barrier, v3.
// r5 bug: ACQUIRE spin -> L2 inv per poll (78us/bar). r6 bug: 256 same-line agent
// fetch_adds serialize at the fabric coherence point (~36us/bar, measured).
// v3: arrival = 256 RELEASE stores to DISTINCT 128B lines (parallel, no RMW);
// block 0's 256 threads poll one flag each (parallel relaxed reads), ONE acquire
// fence, release-store a go word; others poll go relaxed + ONE acquire fence.
// release -> relaxed-load-observing-it -> acquire-fence gives transitive HB.
// bar[0] = go epoch; bar[32 + blk*32] = per-block arrival epoch (128B stride).
__device__ __forceinline__ void gridbar(unsigned* bar, unsigned epoch) {
    __syncthreads();   // this block's phase work done
    int tid = threadIdx.x;
    if (blockIdx.x == 0) {
        if (tid >= 1) {   // thread t polls block t's arrival flag
            const unsigned* f = bar + 32 + tid * 32;
            while (__hip_atomic_load(f, __ATOMIC_RELAXED, __HIP_MEMORY_SCOPE_AGENT) < epoch)
                __builtin_amdgcn_s_sleep(1);
        }
        __syncthreads();  // all 255 arrivals observed
        if (tid == 0) {
            __builtin_amdgcn_fence(__ATOMIC_ACQUIRE, "agent");   // HB with arrivers; one L2 inv
            __hip_atomic_store(bar, epoch, __ATOMIC_RELEASE, __HIP_MEMORY_SCOPE_AGENT);  // go
        }
        __syncthreads();
    } else {
        if (tid == 0) {
            __hip_atomic_store(bar + 32 + blockIdx.x * 32, epoch, __ATOMIC_RELEASE,
                               __HIP_MEMORY_SCOPE_AGENT);        // arrive (publishes writes)
            while (__hip_atomic_load(bar, __ATOMIC_RELAXED, __HIP_MEMORY_SCOPE_AGENT) < epoch)
                __builtin_amdgcn_s_sleep(1);
            __builtin_amdgcn_fence(__ATOMIC_ACQUIRE, "agent");   // one L2 inv per barrier
        }
        __syncthreads();
    }
}

// ---------------- precompute: mean over L, h0/c0, tok init, barrier reset ----------------
__global__ void k_init(const float* __restrict__ hl, const float* __restrict__ Wh0,
                       const float* __restrict__ bh0, const float* __restrict__ Wc0,
                       const float* __restrict__ bc0, float* __restrict__ h_ws,
                       float* __restrict__ c_ws, int* __restrict__ tok_ws,
                       unsigned* __restrict__ barcnt) {
    __shared__ float mean_s[AD];
    int n = blockIdx.x, tid = threadIdx.x;
    if (n == 0)   // replay-safe reset of go + 256 arrival flags (8224 u32)
        for (int i = tid; i < 8256; i += 256) barcnt[i] = 0u;
    for (int a = tid; a < AD; a += 256) {
        float acc = 0.f;
        const float* p = hl + ((size_t)n * LL) * AD + a;
        for (int l = 0; l < LL; ++l) acc += p[(size_t)l * AD];
        mean_s[a] = acc / 196.0f;
    }
    __syncthreads();
    for (int hh = tid; hh < HD; hh += 256) {
        float ah = bh0[hh], ac = bc0[hh];
        for (int k = 0; k < AD; ++k) {
            float m = mean_s[k];
            ah = fmaf(m, Wh0[k * HD + hh], ah);
            ac = fmaf(m, Wc0[k * HD + hh], ac);
        }
        h_ws[n * HD + hh] = fast_tanh(ah);
        c_ws[n * HD + hh] = fast_tanh(ac);
    }
    if (tid == 0) tok_ws[n] = 1;  // START
}

// ---------------- precompute: hl_Wa = hl @ Wa  (12544x512 @ 512x512) ----------------
__global__ void k_hlwa(const float* __restrict__ Amat, const float* __restrict__ Bmat,
                       float* __restrict__ Cmat) {
    __shared__ __attribute__((aligned(16))) float xt[64 * 64];  // (k, m) skewed
    __shared__ __attribute__((aligned(16))) float bs[64 * 68];  // (k, j) stride-68
    int tid = threadIdx.x;
    int lane16 = tid & 15, rowg = tid >> 4;
    int m0 = blockIdx.x * 64, jb = blockIdx.y * 64;
    float acc[4][4] = {};
    for (int ch = 0; ch < 8; ++ch) {
        int kbase = ch * 64;
        __syncthreads();
        for (int it = 0; it < 4; ++it) {
            int k4 = tid & 15;
            int nrow = (tid >> 4) + it * 16;
            float4 v = *(const float4*)&Amat[(size_t)(m0 + nrow) * 512 + kbase + k4 * 4];
            int col = (nrow + k4 * 4) & 63;
            xt[(k4 * 4 + 0) * 64 + col] = v.x;
            xt[(k4 * 4 + 1) * 64 + col] = v.y;
            xt[(k4 * 4 + 2) * 64 + col] = v.z;
            xt[(k4 * 4 + 3) * 64 + col] = v.w;
        }
        for (int it = 0; it < 4; ++it) {
            int r = it * 16 + (tid >> 4);
            int c4 = (tid & 15) * 4;
            *(float4*)&bs[r * 68 + c4] = *(const float4*)&Bmat[(size_t)(kbase + r) * 512 + jb + c4];
        }
        __syncthreads();
#pragma unroll 8
        for (int kk = 0; kk < 64; ++kk) {
            float4 w4 = *(const float4*)&bs[kk * 68 + lane16 * 4];
            float4 h4 = *(const float4*)&xt[kk * 64 + ((rowg * 4 + (kk & ~3)) & 63)];
            float hv[4] = {h4.x, h4.y, h4.z, h4.w};
            float wv[4] = {w4.x, w4.y, w4.z, w4.w};
#pragma unroll
            for (int r = 0; r < 4; ++r)
#pragma unroll
                for (int j = 0; j < 4; ++j) acc[r][j] = fmaf(hv[r], wv[j], acc[r][j]);
        }
    }
    for (int r = 0; r < 4; ++r) {
        float4 o = {acc[r][0], acc[r][1], acc[r][2], acc[r][3]};
        *(float4*)&Cmat[(size_t)(m0 + rowg * 4 + r) * 512 + jb + lane16 * 4] = o;
    }
}

// ---------------- one-shot: pack Wout (fp32 [512][30000]) -> bf16 B-fragments ----------
__global__ void k_wcvt(const float* __restrict__ Wout, unsigned short* __restrict__ WoutB) {
    int id = blockIdx.x * 256 + threadIdx.x;      // 0 .. 1,920,000-1
    int lane = id & 63;
    int kb = (id >> 6) & 15;
    int vb = id >> 10;
    int v  = vb * 16 + (lane & 15);
    int k0 = kb * 32 + (lane >> 4) * 8;
    unsigned int pk[4];
#pragma unroll
    for (int p = 0; p < 4; ++p) {
        unsigned int lo = f2bf(Wout[(size_t)(k0 + 2 * p) * VD + v]);
        unsigned int hi = f2bf(Wout[(size_t)(k0 + 2 * p + 1) * VD + v]);
        pk[p] = lo | (hi << 16);
    }
    *(uint4*)&WoutB[(size_t)id * 8] = make_uint4(pk[0], pk[1], pk[2], pk[3]);
}

// ================= device phase functions (math verbatim from verified kernels) =========

// hua: b in 0..63
__device__ __forceinline__ void do_hua(int b, int tid, float* smem,
        const float* __restrict__ h_ws, const float* __restrict__ Ua,
        float* __restrict__ hua_part) {
    float* xt = smem;          // 4096 floats
    float* us = smem + 4096;   // 4352 floats
    int lane16 = tid & 15, rowg = tid >> 4;
    int s = b & 7, jt = b >> 3;
    int jb = jt * 64, kbase = s * 64;
    float acc[4][4] = {};
    for (int it = 0; it < 4; ++it) {
        int k4 = tid & 15;
        int nrow = (tid >> 4) + it * 16;
        float4 v = *(const float4*)&h_ws[nrow * 512 + kbase + k4 * 4];
        int col = (nrow + k4 * 4) & 63;
        xt[(k4 * 4 + 0) * 64 + col] = v.x;
        xt[(k4 * 4 + 1) * 64 + col] = v.y;
        xt[(k4 * 4 + 2) * 64 + col] = v.z;
        xt[(k4 * 4 + 3) * 64 + col] = v.w;
    }
    for (int it = 0; it < 4; ++it) {
        int r = it * 16 + (tid >> 4);
        int c4 = (tid & 15) * 4;
        *(float4*)&us[r * 68 + c4] = *(const float4*)&Ua[(size_t)(kbase + r) * 512 + jb + c4];
    }
    __syncthreads();
#pragma unroll 8
    for (int kk = 0; kk < 64; ++kk) {
        float4 w4 = *(const float4*)&us[kk * 68 + lane16 * 4];
        float4 h4 = *(const float4*)&xt[kk * 64 + ((rowg * 4 + (kk & ~3)) & 63)];
        float hv[4] = {h4.x, h4.y, h4.z, h4.w};
        float wv[4] = {w4.x, w4.y, w4.z, w4.w};
#pragma unroll
        for (int r = 0; r < 4; ++r)
#pragma unroll
            for (int j = 0; j < 4; ++j) acc[r][j] = fmaf(hv[r], wv[j], acc[r][j]);
    }
    float* gp = hua_part + (size_t)s * NB * HD;
    for (int r = 0; r < 4; ++r) {
        float4 o = {acc[r][0], acc[r][1], acc[r][2], acc[r][3]};
        *(float4*)&gp[(size_t)(rowg * 4 + r) * 512 + jb + lane16 * 4] = o;
    }
}

// att_e: b in 0..191 -> n = b&63, q = b>>6 (3-way row split; per-l math identical)
__device__ __forceinline__ void do_att_e(int b, int tid,
        const float* __restrict__ hlwa, const float* __restrict__ hua_part,
        const float* __restrict__ ba, const float* __restrict__ va,
        float* __restrict__ e_ws) {
    int n = b & 63, q = b >> 6;
    int wave = tid >> 6, lane = tid & 63;
    float4 ua_a = *(const float4*)&ba[lane * 4];
    float4 ua_b = *(const float4*)&ba[256 + lane * 4];
    for (int s = 0; s < 8; ++s) {
        const float* p = hua_part + (size_t)s * NB * HD + n * HD;
        float4 pa = *(const float4*)&p[lane * 4];
        float4 pb = *(const float4*)&p[256 + lane * 4];
        ua_a.x += pa.x; ua_a.y += pa.y; ua_a.z += pa.z; ua_a.w += pa.w;
        ua_b.x += pb.x; ua_b.y += pb.y; ua_b.z += pb.z; ua_b.w += pb.w;
    }
    float4 va_a = *(const float4*)&va[lane * 4];
    float4 va_b = *(const float4*)&va[256 + lane * 4];
    int lstart = q * 66, lend = (q == 2) ? LL : (q * 66 + 66);
    for (int l = lstart + wave; l < lend; l += 4) {
        const float* base = hlwa + ((size_t)n * LL + l) * HD;
        float4 xa = *(const float4*)&base[lane * 4];
        float4 xb = *(const float4*)&base[256 + lane * 4];
        float s = 0.f;
        s = fmaf(fast_tanh(xa.x + ua_a.x), va_a.x, s);
        s = fmaf(fast_tanh(xa.y + ua_a.y), va_a.y, s);
        s = fmaf(fast_tanh(xa.z + ua_a.z), va_a.z, s);
        s = fmaf(fast_tanh(xa.w + ua_a.w), va_a.w, s);
        s = fmaf(fast_tanh(xb.x + ua_b.x), va_b.x, s);
        s = fmaf(fast_tanh(xb.y + ua_b.y), va_b.y, s);
        s = fmaf(fast_tanh(xb.z + ua_b.z), va_b.z, s);
        s = fmaf(fast_tanh(xb.w + ua_b.w), va_b.w, s);
        for (int m = 1; m < 64; m <<= 1) s += __shfl_xor(s, m, 64);
        if (lane == 0) e_ws[n * LL + l] = s;
    }
}

// soft_z: n in 0..63
__device__ __forceinline__ void do_soft_z(int n, int tid, float* smem,
        const float* __restrict__ e_ws, const float* __restrict__ hl,
        const float* __restrict__ h_ws, const float* __restrict__ Wb,
        const float* __restrict__ bb, float* __restrict__ z_ws) {
    float* red = smem;            // 256
    float* alpha = smem + 256;    // 256
    float* zs = smem + 512;       // 512
    // beta at smem[1024]
    float ev = (tid < LL) ? e_ws[n * LL + tid] : -INFINITY;
    red[tid] = ev;
    __syncthreads();
    for (int s = 128; s > 0; s >>= 1) {
        if (tid < s) red[tid] = fmaxf(red[tid], red[tid + s]);
        __syncthreads();
    }
    float m = red[0];
    __syncthreads();
    float a = (tid < LL) ? fast_exp(ev - m) : 0.f;
    red[tid] = a;
    __syncthreads();
    for (int s = 128; s > 0; s >>= 1) {
        if (tid < s) red[tid] += red[tid + s];
        __syncthreads();
    }
    float sum = red[0];
    alpha[tid] = a / sum;
    __syncthreads();
    float bp = h_ws[n * HD + tid] * Wb[tid] + h_ws[n * HD + 256 + tid] * Wb[256 + tid];
    red[tid] = bp;
    __syncthreads();
    for (int s = 128; s > 0; s >>= 1) {
        if (tid < s) red[tid] += red[tid + s];
        __syncthreads();
    }
    if (tid == 0) smem[1024] = fast_sigmoid(red[0] + bb[0]);
    int lq = tid >> 7, ai = tid & 127;
    const float* base = hl + ((size_t)n * LL) * AD + ai * 4;
    float4 acc4 = {0.f, 0.f, 0.f, 0.f};
    int l0 = lq * 98, l1 = l0 + 98;
    for (int l = l0; l < l1; ++l) {
        float al = alpha[l];
        float4 v = *(const float4*)&base[(size_t)l * AD];
        acc4.x = fmaf(al, v.x, acc4.x);
        acc4.y = fmaf(al, v.y, acc4.y);
        acc4.z = fmaf(al, v.z, acc4.z);
        acc4.w = fmaf(al, v.w, acc4.w);
    }
    if (lq == 1) *(float4*)&zs[ai * 4] = acc4;
    __syncthreads();
    if (lq == 0) {
        float4 o = *(const float4*)&zs[ai * 4];
        float b = smem[1024];
        o.x = (o.x + acc4.x) * b;
        o.y = (o.y + acc4.y) * b;
        o.z = (o.z + acc4.z) * b;
        o.w = (o.w + acc4.w) * b;
        *(float4*)&z_ws[n * AD + ai * 4] = o;
    }
}

// gates: b in 0..255
__device__ __forceinline__ void do_gates(int b, int tid, float* smem,
        const float* __restrict__ z_ws, const float* __restrict__ emb,
        const int* __restrict__ tok_ws, const float* __restrict__ h_ws,
        const float* __restrict__ Wx, const float* __restrict__ Wh,
        float* __restrict__ gates_part) {
    float* xt = smem;          // 4096
    float* wsl = smem + 4096;  // 4352
    int lane16 = tid & 15, rowg = tid >> 4;
    int s = b & 7, jt = b >> 3;
    int jb = jt * 64;
    float acc[4][4] = {};
    for (int ch = 0; ch < 3; ++ch) {
        int kbase = s * 192 + ch * 64;
        __syncthreads();
        for (int it = 0; it < 4; ++it) {
            int nrow = (tid >> 4) + it * 16;
            int k4 = tid & 15;
            int gk = kbase + k4 * 4;
            const float* src;
            if (gk < 512)       src = &z_ws[nrow * 512 + gk];
            else if (gk < 1024) src = &emb[(size_t)tok_ws[nrow] * 512 + (gk - 512)];
            else                src = &h_ws[nrow * 512 + (gk - 1024)];
            float4 v = *(const float4*)src;
            int col = (nrow + k4 * 4) & 63;
            xt[(k4 * 4 + 0) * 64 + col] = v.x;
            xt[(k4 * 4 + 1) * 64 + col] = v.y;
            xt[(k4 * 4 + 2) * 64 + col] = v.z;
            xt[(k4 * 4 + 3) * 64 + col] = v.w;
        }
        for (int it = 0; it < 4; ++it) {
            int r = it * 16 + (tid >> 4);
            int gk = kbase + r;
            const float* wrow = (gk < 1024) ? &Wx[(size_t)gk * G4] : &Wh[(size_t)(gk - 1024) * G4];
            int c4 = (tid & 15) * 4;
            *(float4*)&wsl[r * 68 + c4] = *(const float4*)&wrow[jb + c4];
        }
        __syncthreads();
#pragma unroll 8
        for (int kk = 0; kk < 64; ++kk) {
            float4 w4 = *(const float4*)&wsl[kk * 68 + lane16 * 4];
            float4 h4 = *(const float4*)&xt[kk * 64 + ((rowg * 4 + (kk & ~3)) & 63)];
            float hv[4] = {h4.x, h4.y, h4.z, h4.w};
            float wv[4] = {w4.x, w4.y, w4.z, w4.w};
#pragma unroll
            for (int r = 0; r < 4; ++r)
#pragma unroll
                for (int j = 0; j < 4; ++j) acc[r][j] = fmaf(hv[r], wv[j], acc[r][j]);
        }
    }
    float* gp = gates_part + (size_t)s * NB * G4;
    for (int r = 0; r < 4; ++r) {
        float4 o = {acc[r][0], acc[r][1], acc[r][2], acc[r][3]};
        *(float4*)&gp[(size_t)(rowg * 4 + r) * G4 + jb + lane16 * 4] = o;
    }
}

// lstm: b in 0..127
__device__ __forceinline__ void do_lstm(int b, int tid,
        const float* __restrict__ gates_part, const float* __restrict__ b_lstm,
        float* __restrict__ h_ws, float* __restrict__ c_ws,
        unsigned short* __restrict__ hB) {
    int idx = b * 256 + tid;  // 0..32767
    int n = idx >> 9, hh = idx & 511;
    float ig = b_lstm[hh], fg = b_lstm[512 + hh], gg = b_lstm[1024 + hh], og = b_lstm[1536 + hh];
    for (int s = 0; s < 8; ++s) {
        const float* gp = gates_part + (size_t)s * NB * G4 + (size_t)n * G4;
        ig += gp[hh]; fg += gp[512 + hh]; gg += gp[1024 + hh]; og += gp[1536 + hh];
    }
    float c = c_ws[idx];
    float cn = fast_sigmoid(fg) * c + fast_sigmoid(ig) * fast_tanh(gg);
    float hn = fast_sigmoid(og) * fast_tanh(cn);
    c_ws[idx] = cn;
    h_ws[idx] = hn;
    int mb = n >> 4, kb = hh >> 5;
    int lane = (n & 15) + ((hh >> 3) & 3) * 16;
    hB[(((size_t)mb * 16 + kb) * 64 + lane) * 8 + (hh & 7)] = f2bf(hn);
}

// logits: one 128-col vocab tile (0..234); hB staged in two 32KB LDS halves
__device__ __forceinline__ void do_logits(int tile, int tid, float* smem,
        const unsigned short* __restrict__ hB, const unsigned short* __restrict__ WoutB,
        const float* __restrict__ bout, float* __restrict__ pval, int* __restrict__ pidx) {
    unsigned short* hs = (unsigned short*)smem;   // 32 KB = 2048 16B-slots
    float* sv1 = smem + 8192; float* sv2 = smem + 8448;
    int* si1 = (int*)(smem + 8704); int* si2 = (int*)(smem + 8960);
    int w = tid >> 6, lane = tid & 63;
    int jb = tile * 128;
    if (jb > VD - 128) jb = VD - 128;
    int vbw = (jb >> 4) + w * 2;
    const bf16x8* wP = (const bf16x8*)WoutB;
    const bf16x8* hP = (const bf16x8*)hs;
    f32x4 acc[2][4] = {};
    for (int hf = 0; hf < 2; ++hf) {
        __syncthreads();   // prior hs/sv use complete before restage
#pragma unroll
        for (int i = 0; i < 8; ++i) {
            int sbase = i * 256 + w * 64;
            int mb = sbase >> 9, kb2 = (sbase >> 6) & 7;
            int gslot = (mb * 16 + hf * 8 + kb2) * 64;
            gload_lds16(&hB[(size_t)(gslot + lane) * 8], &hs[(size_t)sbase * 8]);
        }
        __syncthreads();   // drains DMA
#pragma unroll 2
        for (int kb2 = 0; kb2 < 8; ++kb2) {
            int kb = hf * 8 + kb2;
            bf16x8 b0 = wP[((size_t)vbw * 16 + kb) * 64 + lane];
            bf16x8 b1 = wP[((size_t)(vbw + 1) * 16 + kb) * 64 + lane];
            bf16x8 a0 = hP[(0 * 8 + kb2) * 64 + lane];
            bf16x8 a1 = hP[(1 * 8 + kb2) * 64 + lane];
            bf16x8 a2 = hP[(2 * 8 + kb2) * 64 + lane];
            bf16x8 a3 = hP[(3 * 8 + kb2) * 64 + lane];
            acc[0][0] = __builtin_amdgcn_mfma_f32_16x16x32_bf16(a0, b0, acc[0][0], 0, 0, 0);
            acc[0][1] = __builtin_amdgcn_mfma_f32_16x16x32_bf16(a1, b0, acc[0][1], 0, 0, 0);
            acc[0][2] = __builtin_amdgcn_mfma_f32_16x16x32_bf16(a2, b0, acc[0][2], 0, 0, 0);
            acc[0][3] = __builtin_amdgcn_mfma_f32_16x16x32_bf16(a3, b0, acc[0][3], 0, 0, 0);
            acc[1][0] = __builtin_amdgcn_mfma_f32_16x16x32_bf16(a0, b1, acc[1][0], 0, 0, 0);
            acc[1][1] = __builtin_amdgcn_mfma_f32_16x16x32_bf16(a1, b1, acc[1][1], 0, 0, 0);
            acc[1][2] = __builtin_amdgcn_mfma_f32_16x16x32_bf16(a2, b1, acc[1][2], 0, 0, 0);
            acc[1][3] = __builtin_amdgcn_mfma_f32_16x16x32_bf16(a3, b1, acc[1][3], 0, 0, 0);
        }
    }
    float bo0 = bout[vbw * 16 + (lane & 15)];
    float bo1 = bout[(vbw + 1) * 16 + (lane & 15)];
    int colb = vbw * 16 + (lane & 15);
    int g = lane >> 4;
#pragma unroll
    for (int mbi = 0; mbi < 4; ++mbi) {
#pragma unroll
        for (int r = 0; r < 4; ++r) {
            int row = mbi * 16 + g * 4 + r;      // C/D: row=(l>>4)*4+reg, col=l&15 (m89)
            float v1 = acc[0][mbi][r] + bo0; int i1 = colb;
            float v2 = acc[1][mbi][r] + bo1; int i2 = colb + 16;
            if (v2 > v1 || (v2 == v1 && i2 < i1)) {
                float tv = v1; int ti = i1; v1 = v2; i1 = i2; v2 = tv; i2 = ti;
            }
            for (int m = 1; m < 16; m <<= 1) {
                float ov1 = __shfl_xor(v1, m, 64); int oi1 = __shfl_xor(i1, m, 64);
                float ov2 = __shfl_xor(v2, m, 64); int oi2 = __shfl_xor(i2, m, 64);
                top2_merge(v1, i1, v2, i2, ov1, oi1, ov2, oi2);
            }
            if ((lane & 15) == 0) {
                sv1[w * 64 + row] = v1; si1[w * 64 + row] = i1;
                sv2[w * 64 + row] = v2; si2[w * 64 + row] = i2;
            }
        }
    }
    __syncthreads();
    if (tid < 64) {
        float v1 = sv1[tid]; int i1 = si1[tid];
        float v2 = sv2[tid]; int i2 = si2[tid];
        for (int q = 1; q < 4; ++q)
            top2_merge(v1, i1, v2, i2, sv1[q * 64 + tid], si1[q * 64 + tid],
                       sv2[q * 64 + tid], si2[q * 64 + tid]);
        pval[(size_t)tid * NC2 + tile * 2 + 0] = v1;
        pval[(size_t)tid * NC2 + tile * 2 + 1] = v2;
        pidx[(size_t)tid * NC2 + tile * 2 + 0] = i1;
        pidx[(size_t)tid * NC2 + tile * 2 + 1] = i2;
    }
}

// argmax: n in 0..63, wave 0 only
__device__ __forceinline__ void do_argmax(int n, int tid, int t,
        const float* __restrict__ pval, const int* __restrict__ pidx,
        const float* __restrict__ h_ws, const float* __restrict__ Wout,
        const float* __restrict__ bout, int* __restrict__ tok_ws, int* __restrict__ out) {
    if (tid >= 64) return;
    int lane = tid;
    const float* pv = pval + (size_t)n * NC2;
    const int*   pi = pidx + (size_t)n * NC2;
    float cv[8]; int ci[8];
#pragma unroll
    for (int q = 0; q < 8; ++q) {
        int i = q * 64 + lane;
        bool ok = i < NC2;
        cv[q] = ok ? pv[i] : -INFINITY;
        ci[q] = ok ? pi[i] : 0x7fffffff;
    }
    int picks[4];
#pragma unroll
    for (int c = 0; c < 4; ++c) {
        float best = -INFINITY; int bi = 0x7fffffff;
#pragma unroll
        for (int q = 0; q < 8; ++q) {
            bool skip = false;
#pragma unroll
            for (int p = 0; p < 4; ++p) skip = skip || (p < c && ci[q] == picks[p]);
            if (!skip && (cv[q] > best || (cv[q] == best && ci[q] < bi))) { best = cv[q]; bi = ci[q]; }
        }
        for (int m = 1; m < 64; m <<= 1) {
            float ov = __shfl_xor(best, m, 64);
            int   oi = __shfl_xor(bi, m, 64);
            if (ov > best || (ov == best && oi < bi)) { best = ov; bi = oi; }
        }
        picks[c] = bi;
    }
    const float* hr = h_ws + (size_t)n * HD;
    float hv[8];
#pragma unroll
    for (int j = 0; j < 8; ++j) hv[j] = hr[lane * 8 + j];
    float s0 = 0.f, s1 = 0.f, s2 = 0.f, s3 = 0.f;
#pragma unroll
    for (int j = 0; j < 8; ++j) {
        size_t krow = (size_t)(lane * 8 + j) * VD;
        s0 = fmaf(hv[j], Wout[krow + picks[0]], s0);
        s1 = fmaf(hv[j], Wout[krow + picks[1]], s1);
        s2 = fmaf(hv[j], Wout[krow + picks[2]], s2);
        s3 = fmaf(hv[j], Wout[krow + picks[3]], s3);
    }
    for (int m = 1; m < 64; m <<= 1) {
        s0 += __shfl_xor(s0, m, 64);
        s1 += __shfl_xor(s1, m, 64);
        s2 += __shfl_xor(s2, m, 64);
        s3 += __shfl_xor(s3, m, 64);
    }
    if (lane == 0) {
        float pex[4] = {s0 + bout[picks[0]], s1 + bout[picks[1]],
                        s2 + bout[picks[2]], s3 + bout[picks[3]]};
        float best = pex[0]; int bi = picks[0];
        for (int c = 1; c < 4; ++c)
            if (pex[c] > best || (pex[c] == best && picks[c] < bi)) { best = pex[c]; bi = picks[c]; }
        tok_ws[n] = bi;
        out[n * TS + t] = bi;
    }
}

// ================= persistent mega-kernel: all 20 steps, flag-tree grid barrier =========
__global__ void __launch_bounds__(256)
k_steps(const float* hl, const float* emb, const float* Ua, const float* ba,
        const float* va, const float* Wb, const float* bb, const float* Wx,
        const float* Wh, const float* b_lstm, const float* Wout, const float* bout,
        const unsigned short* WoutB, const float* hlwa,
        float* h_ws, float* c_ws, float* z_ws, float* e_ws, int* tok_ws,
        float* hua_part, float* gates_part, float* pval, int* pidx,
        unsigned short* hB, int* out, unsigned* barcnt) {
    __shared__ __attribute__((aligned(16))) float smem[9472];   // 37 KB union
    int blk = blockIdx.x, tid = threadIdx.x;
    unsigned epoch = 0;
#define GSYNC() do { ++epoch; gridbar(barcnt, epoch); } while (0)

    // prologue: attention pipeline for t=0
    if (blk < 64) do_hua(blk, tid, smem, h_ws, Ua, hua_part);
    GSYNC();
    if (blk < 192) do_att_e(blk, tid, hlwa, hua_part, ba, va, e_ws);
    GSYNC();
    if (blk < 64) do_soft_z(blk, tid, smem, e_ws, hl, h_ws, Wb, bb, z_ws);
    GSYNC();

    for (int t = 0; t < TS; ++t) {
        // A: gates(t)  [z(t), tok(t), h(t)]
        do_gates(blk, tid, smem, z_ws, emb, tok_ws, h_ws, Wx, Wh, gates_part);
        GSYNC();
        // B: lstm(t) -> h(t+1), c, hB
        if (blk < 128) do_lstm(blk, tid, gates_part, b_lstm, h_ws, c_ws, hB);
        GSYNC();
        // C: logits(t) on blocks 0..191 (235 tiles; double-duty on 149..191 so the
        //    collector block 0 stays off the barrier critical path) || hua(t+1) on 192..255
        if (blk < 192) {
            do_logits(blk, tid, smem, hB, WoutB, bout, pval, pidx);
            if (blk >= 149) do_logits(blk + 43, tid, smem, hB, WoutB, bout, pval, pidx);
        } else if (t < TS - 1) {
            do_hua(blk - 192, tid, smem, h_ws, Ua, hua_part);
        }
        GSYNC();
        // D: argmax(t) -> tok(t+1), out  ||  att_e(t+1)
        if (blk < 64) do_argmax(blk, tid, t, pval, pidx, h_ws, Wout, bout, tok_ws, out);
        else if (t < TS - 1) do_att_e(blk - 64, tid, hlwa, hua_part, ba, va, e_ws);
        GSYNC();
        // E: soft_z(t+1)
        if (blk < 64 && t < TS - 1)
            do_soft_z(blk, tid, smem, e_ws, hl, h_ws, Wb, bb, z_ws);
        GSYNC();
    }
#undef GSYNC
}

extern "C" void kernel_launch(void* const* d_in, const int* in_sizes, int n_in,
                              void* d_out, int out_size, void* d_ws, size_t ws_size,
                              hipStream_t stream) {
    const float* hl     = (const float*)d_in[0];
    const float* emb    = (const float*)d_in[1];
    const float* Wh0    = (const float*)d_in[2];
    const float* bh0    = (const float*)d_in[3];
    const float* Wc0    = (const float*)d_in[4];
    const float* bc0    = (const float*)d_in[5];
    const float* Wa     = (const float*)d_in[6];
    const float* Ua     = (const float*)d_in[7];
    const float* ba     = (const float*)d_in[8];
    const float* va     = (const float*)d_in[9];
    const float* Wb     = (const float*)d_in[10];
    const float* bb     = (const float*)d_in[11];
    const float* Wx     = (const float*)d_in[12];
    const float* Wh     = (const float*)d_in[13];
    const float* b_lstm = (const float*)d_in[14];
    const float* Wout   = (const float*)d_in[15];
    const float* bout   = (const float*)d_in[16];

    float* ws         = (float*)d_ws;
    float* hlwa       = ws;                          // 6422528
    float* h_ws       = ws + 6422528;                // 32768
    float* c_ws       = h_ws + 32768;                // 32768
    float* z_ws       = c_ws + 32768;                // 32768
    float* e_ws       = z_ws + 32768;                // 12544
    int*   tok_ws     = (int*)(e_ws + 12544);        // 64
    float* hua_part   = e_ws + 12544 + 64;           // 8*64*512 = 262144
    float* gates_part = hua_part + 262144;           // 8*64*2048 = 1048576
    float* pval       = gates_part + 1048576;        // 64*470 = 30080
    int*   pidx       = (int*)(pval + 64 * NC2);     // 30080
    unsigned short* hB    = (unsigned short*)(pval + 2 * 64 * NC2);          // 32768 u16
    unsigned short* WoutB = (unsigned short*)(pval + 2 * 64 * NC2 + 16384);  // 15.36M u16
    unsigned* barcnt  = (unsigned*)(ws + 15600704);  // go + 256 flag lines (8224 u32)
    int*   out        = (int*)d_out;

    k_init<<<64, 256, 0, stream>>>(hl, Wh0, bh0, Wc0, bc0, h_ws, c_ws, tok_ws, barcnt);
    k_wcvt<<<7500, 256, 0, stream>>>(Wout, WoutB);
    k_hlwa<<<dim3(196, 8), 256, 0, stream>>>(hl, Wa, hlwa);
    k_steps<<<NBLK, 256, 0, stream>>>(hl, emb, Ua, ba, va, Wb, bb, Wx, Wh, b_lstm,
                                      Wout, bout, WoutB, hlwa, h_ws, c_ws, z_ws, e_ws,
                                      tok_ws, hua_part, gates_part, pval, pidx, hB, out,
                                      barcnt);
}

// Round 8
// 2215.871 us; speedup vs baseline: 3.7369x; 1.6282x over previous
//
#include <hip/hip_runtime.h>
#include <math.h>

#define NB   64      // batch
#define LL   196     // regions
#define AD   512     // image feat dim
#define HD   512     // hidden
#define VD   30000   // vocab
#define TS   20      // steps
#define G4   2048    // 4*H
#define NBL  235     // ceil(30000/128) logits tiles
#define NC2  (NBL * 2)   // top-2 candidates per tile per row = 470

typedef __bf16 bf16x8 __attribute__((ext_vector_type(8)));
typedef float  f32x4  __attribute__((ext_vector_type(4)));

__device__ __forceinline__ float fast_tanh(float x) {
    float e = __builtin_exp2f(x * 2.8853900817779268f);   // exp(2x)
    return 1.0f - 2.0f / (e + 1.0f);
}
__device__ __forceinline__ float fast_sigmoid(float x) {
    return 1.0f / (1.0f + __builtin_exp2f(-x * 1.4426950408889634f));
}
__device__ __forceinline__ float fast_exp(float x) {
    return __builtin_exp2f(x * 1.4426950408889634f);
}
__device__ __forceinline__ unsigned short f2bf(float f) {   // RNE fp32->bf16
    unsigned int u = __float_as_uint(f);
    u += 0x7fffu + ((u >> 16) & 1u);
    return (unsigned short)(u >> 16);
}
// async global->LDS DMA, 16B per lane; lds base must be wave-uniform
__device__ __forceinline__ void gload_lds16(const void* g, void* l) {
    __builtin_amdgcn_global_load_lds((const __attribute__((address_space(1))) void*)g,
                                     (__attribute__((address_space(3))) void*)l, 16, 0, 0);
}
// merge two (top1, top2) candidate pairs, tie-break: smaller index wins
__device__ __forceinline__ void top2_merge(float& v1, int& i1, float& v2, int& i2,
                                           float ov1, int oi1, float ov2, int oi2) {
    if (ov1 > v1 || (ov1 == v1 && oi1 < i1)) {
        float sv = v1; int si = i1;
        v1 = ov1; i1 = oi1;
        if (ov2 > sv || (ov2 == sv && oi2 < si)) { v2 = ov2; i2 = oi2; }
        else { v2 = sv; i2 = si; }
    } else {
        if (ov1 > v2 || (ov1 == v2 && oi1 < i2)) { v2 = ov1; i2 = oi1; }
    }
}

// ---------------- precompute: mean over L, h0/c0, tok init ----------------
__global__ void k_init(const float* __restrict__ hl, const float* __restrict__ Wh0,
                       const float* __restrict__ bh0, const float* __restrict__ Wc0,
                       const float* __restrict__ bc0, float* __restrict__ h_ws,
                       float* __restrict__ c_ws, int* __restrict__ tok_ws) {
    __shared__ float mean_s[AD];
    int n = blockIdx.x, tid = threadIdx.x;
    for (int a = tid; a < AD; a += 256) {
        float acc = 0.f;
        const float* p = hl + ((size_t)n * LL) * AD + a;
        for (int l = 0; l < LL; ++l) acc += p[(size_t)l * AD];
        mean_s[a] = acc / 196.0f;
    }
    __syncthreads();
    for (int hh = tid; hh < HD; hh += 256) {
        float ah = bh0[hh], ac = bc0[hh];
        for (int k = 0; k < AD; ++k) {
            float m = mean_s[k];
            ah = fmaf(m, Wh0[k * HD + hh], ah);
            ac = fmaf(m, Wc0[k * HD + hh], ac);
        }
        h_ws[n * HD + hh] = fast_tanh(ah);
        c_ws[n * HD + hh] = fast_tanh(ac);
    }
    if (tid == 0) tok_ws[n] = 1;  // START
}

// ---------------- precompute: hl_Wa = hl @ Wa  (12544x512 @ 512x512) ----------------
__global__ void k_hlwa(const float* __restrict__ Amat, const float* __restrict__ Bmat,
                       float* __restrict__ Cmat) {
    __shared__ __attribute__((aligned(16))) float xt[64 * 64];  // (k, m) skewed
    __shared__ __attribute__((aligned(16))) float bs[64 * 68];  // (k, j) stride-68
    int tid = threadIdx.x;
    int lane16 = tid & 15, rowg = tid >> 4;
    int m0 = blockIdx.x * 64, jb = blockIdx.y * 64;
    float acc[4][4] = {};
    for (int ch = 0; ch < 8; ++ch) {
        int kbase = ch * 64;
        __syncthreads();
        for (int it = 0; it < 4; ++it) {
            int k4 = tid & 15;
            int nrow = (tid >> 4) + it * 16;
            float4 v = *(const float4*)&Amat[(size_t)(m0 + nrow) * 512 + kbase + k4 * 4];
            int col = (nrow + k4 * 4) & 63;
            xt[(k4 * 4 + 0) * 64 + col] = v.x;
            xt[(k4 * 4 + 1) * 64 + col] = v.y;
            xt[(k4 * 4 + 2) * 64 + col] = v.z;
            xt[(k4 * 4 + 3) * 64 + col] = v.w;
        }
        for (int it = 0; it < 4; ++it) {
            int r = it * 16 + (tid >> 4);
            int c4 = (tid & 15) * 4;
            *(float4*)&bs[r * 68 + c4] = *(const float4*)&Bmat[(size_t)(kbase + r) * 512 + jb + c4];
        }
        __syncthreads();
#pragma unroll 8
        for (int kk = 0; kk < 64; ++kk) {
            float4 w4 = *(const float4*)&bs[kk * 68 + lane16 * 4];
            float4 h4 = *(const float4*)&xt[kk * 64 + ((rowg * 4 + (kk & ~3)) & 63)];
            float hv[4] = {h4.x, h4.y, h4.z, h4.w};
            float wv[4] = {w4.x, w4.y, w4.z, w4.w};
#pragma unroll
            for (int r = 0; r < 4; ++r)
#pragma unroll
                for (int j = 0; j < 4; ++j) acc[r][j] = fmaf(hv[r], wv[j], acc[r][j]);
        }
    }
    for (int r = 0; r < 4; ++r) {
        float4 o = {acc[r][0], acc[r][1], acc[r][2], acc[r][3]};
        *(float4*)&Cmat[(size_t)(m0 + rowg * 4 + r) * 512 + jb + lane16 * 4] = o;
    }
}

// ---------------- one-shot: pack Wout (fp32 [512][30000]) -> bf16 B-fragments ----------
__global__ void k_wcvt(const float* __restrict__ Wout, unsigned short* __restrict__ WoutB) {
    int id = blockIdx.x * 256 + threadIdx.x;      // 0 .. 1,920,000-1
    int lane = id & 63;
    int kb = (id >> 6) & 15;
    int vb = id >> 10;
    int v  = vb * 16 + (lane & 15);
    int k0 = kb * 32 + (lane >> 4) * 8;
    unsigned int pk[4];
#pragma unroll
    for (int p = 0; p < 4; ++p) {
        unsigned int lo = f2bf(Wout[(size_t)(k0 + 2 * p) * VD + v]);
        unsigned int hi = f2bf(Wout[(size_t)(k0 + 2 * p + 1) * VD + v]);
        pk[p] = lo | (hi << 16);
    }
    *(uint4*)&WoutB[(size_t)id * 8] = make_uint4(pk[0], pk[1], pk[2], pk[3]);
}

// ---------------- per step: hua_part[s] = h @ Ua[kslice]  (K-split 8, Ua LDS-staged) ----------------
__global__ void k_hua(const float* __restrict__ h_ws, const float* __restrict__ Ua,
                      float* __restrict__ hua_part) {
    __shared__ __attribute__((aligned(16))) float xt[64 * 64];
    __shared__ __attribute__((aligned(16))) float us[64 * 68];
    int tid = threadIdx.x;
    int lane16 = tid & 15, rowg = tid >> 4;
    int s = blockIdx.x & 7, jt = blockIdx.x >> 3;
    int jb = jt * 64, kbase = s * 64;
    float acc[4][4] = {};
    for (int it = 0; it < 4; ++it) {
        int k4 = tid & 15;
        int nrow = (tid >> 4) + it * 16;
        float4 v = *(const float4*)&h_ws[nrow * 512 + kbase + k4 * 4];
        int col = (nrow + k4 * 4) & 63;
        xt[(k4 * 4 + 0) * 64 + col] = v.x;
        xt[(k4 * 4 + 1) * 64 + col] = v.y;
        xt[(k4 * 4 + 2) * 64 + col] = v.z;
        xt[(k4 * 4 + 3) * 64 + col] = v.w;
    }
    for (int it = 0; it < 4; ++it) {
        int r = it * 16 + (tid >> 4);
        int c4 = (tid & 15) * 4;
        *(float4*)&us[r * 68 + c4] = *(const float4*)&Ua[(size_t)(kbase + r) * 512 + jb + c4];
    }
    __syncthreads();
#pragma unroll 8
    for (int kk = 0; kk < 64; ++kk) {
        float4 w4 = *(const float4*)&us[kk * 68 + lane16 * 4];
        float4 h4 = *(const float4*)&xt[kk * 64 + ((rowg * 4 + (kk & ~3)) & 63)];
        float hv[4] = {h4.x, h4.y, h4.z, h4.w};
        float wv[4] = {w4.x, w4.y, w4.z, w4.w};
#pragma unroll
        for (int r = 0; r < 4; ++r)
#pragma unroll
            for (int j = 0; j < 4; ++j) acc[r][j] = fmaf(hv[r], wv[j], acc[r][j]);
    }
    float* gp = hua_part + (size_t)s * NB * HD;
    for (int r = 0; r < 4; ++r) {
        float4 o = {acc[r][0], acc[r][1], acc[r][2], acc[r][3]};
        *(float4*)&gp[(size_t)(rowg * 4 + r) * 512 + jb + lane16 * 4] = o;
    }
}

// ---------------- per step (fused): e scores + softmax + beta gate + z (512 thr) ----------------
// verified bit-exact in round 2: e-phase 8 waves; softmax/z padded with identity elements.
__global__ void k_attz(const float* __restrict__ hlwa, const float* __restrict__ hua_part,
                       const float* __restrict__ ba, const float* __restrict__ va,
                       const float* __restrict__ hl, const float* __restrict__ h_ws,
                       const float* __restrict__ Wb, const float* __restrict__ bb,
                       float* __restrict__ z_ws) {
    __shared__ float u0[512];
    __shared__ float earr[256];
    __shared__ float red[512];
    __shared__ float alpha[256];
    __shared__ float zs[512];
    __shared__ float beta_s;
    int n = blockIdx.x, tid = threadIdx.x;     // 512 threads
    int wave = tid >> 6, lane = tid & 63;
    {   // u = ba + sum_s hua_part[s][n]  (same per-element add order)
        float acc = ba[tid];
        for (int s = 0; s < 8; ++s) acc += hua_part[(size_t)s * NB * HD + n * HD + tid];
        u0[tid] = acc;
    }
    __syncthreads();
    float4 ua_a = *(const float4*)&u0[lane * 4];
    float4 ua_b = *(const float4*)&u0[256 + lane * 4];
    float4 va_a = *(const float4*)&va[lane * 4];
    float4 va_b = *(const float4*)&va[256 + lane * 4];
    for (int l = wave; l < LL; l += 8) {
        const float* base = hlwa + ((size_t)n * LL + l) * HD;
        float4 xa = *(const float4*)&base[lane * 4];
        float4 xb = *(const float4*)&base[256 + lane * 4];
        float s = 0.f;
        s = fmaf(fast_tanh(xa.x + ua_a.x), va_a.x, s);
        s = fmaf(fast_tanh(xa.y + ua_a.y), va_a.y, s);
        s = fmaf(fast_tanh(xa.z + ua_a.z), va_a.z, s);
        s = fmaf(fast_tanh(xa.w + ua_a.w), va_a.w, s);
        s = fmaf(fast_tanh(xb.x + ua_b.x), va_b.x, s);
        s = fmaf(fast_tanh(xb.y + ua_b.y), va_b.y, s);
        s = fmaf(fast_tanh(xb.z + ua_b.z), va_b.z, s);
        s = fmaf(fast_tanh(xb.w + ua_b.w), va_b.w, s);
        for (int m = 1; m < 64; m <<= 1) s += __shfl_xor(s, m, 64);
        if (lane == 0) earr[l] = s;
    }
    __syncthreads();
    float ev = (tid < LL) ? earr[tid] : -INFINITY;
    red[tid] = ev;
    __syncthreads();
    for (int s = 256; s > 0; s >>= 1) {
        if (tid < s) red[tid] = fmaxf(red[tid], red[tid + s]);
        __syncthreads();
    }
    float m = red[0];
    __syncthreads();
    float a = (tid < LL) ? fast_exp(ev - m) : 0.f;
    red[tid] = a;
    __syncthreads();
    for (int s = 256; s > 0; s >>= 1) {
        if (tid < s) red[tid] += red[tid + s];
        __syncthreads();
    }
    float sum = red[0];
    if (tid < 256) alpha[tid] = a / sum;
    __syncthreads();
    float bp = (tid < 256)
        ? (h_ws[n * HD + tid] * Wb[tid] + h_ws[n * HD + 256 + tid] * Wb[256 + tid]) : 0.f;
    red[tid] = bp;
    __syncthreads();
    for (int s = 256; s > 0; s >>= 1) {
        if (tid < s) red[tid] += red[tid + s];
        __syncthreads();
    }
    if (tid == 0) beta_s = fast_sigmoid(red[0] + bb[0]);
    float4 acc4 = {0.f, 0.f, 0.f, 0.f};
    int lq = (tid >> 7) & 1, ai = tid & 127;
    if (tid < 256) {
        const float* base = hl + ((size_t)n * LL) * AD + ai * 4;
        int l0 = lq * 98, l1 = l0 + 98;
        for (int l = l0; l < l1; ++l) {
            float al = alpha[l];
            float4 v = *(const float4*)&base[(size_t)l * AD];
            acc4.x = fmaf(al, v.x, acc4.x);
            acc4.y = fmaf(al, v.y, acc4.y);
            acc4.z = fmaf(al, v.z, acc4.z);
            acc4.w = fmaf(al, v.w, acc4.w);
        }
        if (lq == 1) *(float4*)&zs[ai * 4] = acc4;
    }
    __syncthreads();
    if (tid < 128) {
        float4 o = *(const float4*)&zs[ai * 4];
        float b = beta_s;
        o.x = (o.x + acc4.x) * b;
        o.y = (o.y + acc4.y) * b;
        o.z = (o.z + acc4.z) * b;
        o.w = (o.w + acc4.w) * b;
        *(float4*)&z_ws[n * AD + ai * 4] = o;
    }
}

// ---------------- per step: gates partial GEMM  X[64x1536] @ W[1536x2048], K split 8 ----------------
__global__ void k_gates(const float* __restrict__ z_ws, const float* __restrict__ emb,
                        const int* __restrict__ tok_ws, const float* __restrict__ h_ws,
                        const float* __restrict__ Wx, const float* __restrict__ Wh,
                        float* __restrict__ gates_part) {
    __shared__ __attribute__((aligned(16))) float xt[64 * 64];
    __shared__ __attribute__((aligned(16))) float wsl[64 * 68];
    int tid = threadIdx.x;
    int lane16 = tid & 15, rowg = tid >> 4;
    int s = blockIdx.x & 7, jt = blockIdx.x >> 3;
    int jb = jt * 64;
    float acc[4][4] = {};
    for (int ch = 0; ch < 3; ++ch) {
        int kbase = s * 192 + ch * 64;
        __syncthreads();
        for (int it = 0; it < 4; ++it) {
            int nrow = (tid >> 4) + it * 16;
            int k4 = tid & 15;
            int gk = kbase + k4 * 4;
            const float* src;
            if (gk < 512)       src = &z_ws[nrow * 512 + gk];
            else if (gk < 1024) src = &emb[(size_t)tok_ws[nrow] * 512 + (gk - 512)];
            else                src = &h_ws[nrow * 512 + (gk - 1024)];
            float4 v = *(const float4*)src;
            int col = (nrow + k4 * 4) & 63;
            xt[(k4 * 4 + 0) * 64 + col] = v.x;
            xt[(k4 * 4 + 1) * 64 + col] = v.y;
            xt[(k4 * 4 + 2) * 64 + col] = v.z;
            xt[(k4 * 4 + 3) * 64 + col] = v.w;
        }
        for (int it = 0; it < 4; ++it) {
            int r = it * 16 + (tid >> 4);
            int gk = kbase + r;
            const float* wrow = (gk < 1024) ? &Wx[(size_t)gk * G4] : &Wh[(size_t)(gk - 1024) * G4];
            int c4 = (tid & 15) * 4;
            *(float4*)&wsl[r * 68 + c4] = *(const float4*)&wrow[jb + c4];
        }
        __syncthreads();
#pragma unroll 8
        for (int kk = 0; kk < 64; ++kk) {
            float4 w4 = *(const float4*)&wsl[kk * 68 + lane16 * 4];
            float4 h4 = *(const float4*)&xt[kk * 64 + ((rowg * 4 + (kk & ~3)) & 63)];
            float hv[4] = {h4.x, h4.y, h4.z, h4.w};
            float wv[4] = {w4.x, w4.y, w4.z, w4.w};
#pragma unroll
            for (int r = 0; r < 4; ++r)
#pragma unroll
                for (int j = 0; j < 4; ++j) acc[r][j] = fmaf(hv[r], wv[j], acc[r][j]);
        }
    }
    float* gp = gates_part + (size_t)s * NB * G4;
    for (int r = 0; r < 4; ++r) {
        float4 o = {acc[r][0], acc[r][1], acc[r][2], acc[r][3]};
        *(float4*)&gp[(size_t)(rowg * 4 + r) * G4 + jb + lane16 * 4] = o;
    }
}

// ---------------- per step: reduce gate partials + LSTM cell update (+ bf16 h pack) ----------------
__global__ void k_lstm(const float* __restrict__ gates_part, const float* __restrict__ b_lstm,
                       float* __restrict__ h_ws, float* __restrict__ c_ws,
                       unsigned short* __restrict__ hB) {
    int idx = blockIdx.x * 256 + threadIdx.x;  // 0..32767
    int n = idx >> 9, hh = idx & 511;
    float ig = b_lstm[hh], fg = b_lstm[512 + hh], gg = b_lstm[1024 + hh], og = b_lstm[1536 + hh];
    for (int s = 0; s < 8; ++s) {
        const float* gp = gates_part + (size_t)s * NB * G4 + (size_t)n * G4;
        ig += gp[hh]; fg += gp[512 + hh]; gg += gp[1024 + hh]; og += gp[1536 + hh];
    }
    float c = c_ws[idx];
    float cn = fast_sigmoid(fg) * c + fast_sigmoid(ig) * fast_tanh(gg);
    float hn = fast_sigmoid(og) * fast_tanh(cn);
    c_ws[idx] = cn;
    h_ws[idx] = hn;
    // pack h into bf16 A-fragment layout [mb(4)][kb(16)][lane(64)][j(8)]
    int mb = n >> 4, kb = hh >> 5;
    int lane = (n & 15) + ((hh >> 3) & 3) * 16;
    hB[(((size_t)mb * 16 + kb) * 64 + lane) * 8 + (hh & 7)] = f2bf(hn);
}

// ---------------- per step: approx logits via bf16 MFMA (hB LDS-staged); top-2/block ----------------
__global__ void k_logits(const unsigned short* __restrict__ hB,
                         const unsigned short* __restrict__ WoutB,
                         const float* __restrict__ bout,
                         float* __restrict__ pval, int* __restrict__ pidx) {
    __shared__ __attribute__((aligned(16))) unsigned short hs[4096 * 8];  // 64KB, fragment-linear
    __shared__ float sv1[4][64]; __shared__ int si1[4][64];
    __shared__ float sv2[4][64]; __shared__ int si2[4][64];
    int tid = threadIdx.x;
    int w = tid >> 6, lane = tid & 63;
    int jb = blockIdx.x * 128;
    if (jb > VD - 128) jb = VD - 128;            // clamp last tile (dups deduped later)
#pragma unroll
    for (int i = 0; i < 16; ++i) {
        int base = i * 256 + w * 64;             // 16B-slot index
        gload_lds16(&hB[(size_t)(base + lane) * 8], &hs[(size_t)base * 8]);
    }
    __syncthreads();                             // drains DMA
    int jbv = jb >> 4;
    int vbw = jbv + w * 2;                       // this wave's first vb tile
    const bf16x8* wP = (const bf16x8*)WoutB;
    const bf16x8* hP = (const bf16x8*)hs;
    f32x4 acc[2][4] = {};                        // [vbi][mbi]
#pragma unroll 2
    for (int kb = 0; kb < 16; ++kb) {
        bf16x8 b0 = wP[((size_t)vbw * 16 + kb) * 64 + lane];
        bf16x8 b1 = wP[((size_t)(vbw + 1) * 16 + kb) * 64 + lane];
        bf16x8 a0 = hP[(0 * 16 + kb) * 64 + lane];
        bf16x8 a1 = hP[(1 * 16 + kb) * 64 + lane];
        bf16x8 a2 = hP[(2 * 16 + kb) * 64 + lane];
        bf16x8 a3 = hP[(3 * 16 + kb) * 64 + lane];
        acc[0][0] = __builtin_amdgcn_mfma_f32_16x16x32_bf16(a0, b0, acc[0][0], 0, 0, 0);
        acc[0][1] = __builtin_amdgcn_mfma_f32_16x16x32_bf16(a1, b0, acc[0][1], 0, 0, 0);
        acc[0][2] = __builtin_amdgcn_mfma_f32_16x16x32_bf16(a2, b0, acc[0][2], 0, 0, 0);
        acc[0][3] = __builtin_amdgcn_mfma_f32_16x16x32_bf16(a3, b0, acc[0][3], 0, 0, 0);
        acc[1][0] = __builtin_amdgcn_mfma_f32_16x16x32_bf16(a0, b1, acc[1][0], 0, 0, 0);
        acc[1][1] = __builtin_amdgcn_mfma_f32_16x16x32_bf16(a1, b1, acc[1][1], 0, 0, 0);
        acc[1][2] = __builtin_amdgcn_mfma_f32_16x16x32_bf16(a2, b1, acc[1][2], 0, 0, 0);
        acc[1][3] = __builtin_amdgcn_mfma_f32_16x16x32_bf16(a3, b1, acc[1][3], 0, 0, 0);
    }
    float bo0 = bout[vbw * 16 + (lane & 15)];
    float bo1 = bout[(vbw + 1) * 16 + (lane & 15)];
    int colb = vbw * 16 + (lane & 15);
    int g = lane >> 4;
#pragma unroll
    for (int mbi = 0; mbi < 4; ++mbi) {
#pragma unroll
        for (int r = 0; r < 4; ++r) {
            int row = mbi * 16 + g * 4 + r;      // C/D: row=(l>>4)*4+reg, col=l&15 (m89)
            float v1 = acc[0][mbi][r] + bo0; int i1 = colb;
            float v2 = acc[1][mbi][r] + bo1; int i2 = colb + 16;
            if (v2 > v1 || (v2 == v1 && i2 < i1)) {
                float tv = v1; int ti = i1; v1 = v2; i1 = i2; v2 = tv; i2 = ti;
            }
            for (int m = 1; m < 16; m <<= 1) {   // butterfly within 16-lane row group
                float ov1 = __shfl_xor(v1, m, 64); int oi1 = __shfl_xor(i1, m, 64);
                float ov2 = __shfl_xor(v2, m, 64); int oi2 = __shfl_xor(i2, m, 64);
                top2_merge(v1, i1, v2, i2, ov1, oi1, ov2, oi2);
            }
            if ((lane & 15) == 0) {
                sv1[w][row] = v1; si1[w][row] = i1;
                sv2[w][row] = v2; si2[w][row] = i2;
            }
        }
    }
    __syncthreads();
    if (tid < 64) {                              // cross-wave merge -> block top-2 per row
        float v1 = sv1[0][tid]; int i1 = si1[0][tid];
        float v2 = sv2[0][tid]; int i2 = si2[0][tid];
        for (int q = 1; q < 4; ++q)
            top2_merge(v1, i1, v2, i2, sv1[q][tid], si1[q][tid], sv2[q][tid], si2[q][tid]);
        pval[(size_t)tid * NC2 + blockIdx.x * 2 + 0] = v1;
        pval[(size_t)tid * NC2 + blockIdx.x * 2 + 1] = v2;
        pidx[(size_t)tid * NC2 + blockIdx.x * 2 + 0] = i1;
        pidx[(size_t)tid * NC2 + blockIdx.x * 2 + 1] = i2;
    }
}

// ---------------- per step (fused): argmax(t) [blocks 0..63] || hua(t+1) [blocks 64..127] ----
// independent work: argmax reads pval/pidx/h_ws/Wout, writes tok_ws/out;
// hua reads h_ws/Ua, writes hua_part. Both depend only on lstm(t)+logits(t).
__global__ void k_axhua(const float* __restrict__ pval, const int* __restrict__ pidx,
                        const float* __restrict__ h_ws, const float* __restrict__ Wout,
                        const float* __restrict__ bout, int* __restrict__ tok_ws,
                        int* __restrict__ out, int t,
                        const float* __restrict__ Ua, float* __restrict__ hua_part) {
    __shared__ __attribute__((aligned(16))) float xt[64 * 64];
    __shared__ __attribute__((aligned(16))) float us[64 * 68];
    int blk = blockIdx.x, tid = threadIdx.x;
    if (blk < 64) {
        // ---- argmax body (verbatim round-3 k_argmax; wave 0 only, no barriers) ----
        if (tid >= 64) return;
        int n = blk, lane = tid;
        const float* pv = pval + (size_t)n * NC2;
        const int*   pi = pidx + (size_t)n * NC2;
        float cv[8]; int ci[8];
#pragma unroll
        for (int q = 0; q < 8; ++q) {
            int i = q * 64 + lane;
            bool ok = i < NC2;
            cv[q] = ok ? pv[i] : -INFINITY;
            ci[q] = ok ? pi[i] : 0x7fffffff;
        }
        int picks[4];
#pragma unroll
        for (int c = 0; c < 4; ++c) {
            float best = -INFINITY; int bi = 0x7fffffff;
#pragma unroll
            for (int q = 0; q < 8; ++q) {
                bool skip = false;
#pragma unroll
                for (int p = 0; p < 4; ++p) skip = skip || (p < c && ci[q] == picks[p]);
                if (!skip && (cv[q] > best || (cv[q] == best && ci[q] < bi))) { best = cv[q]; bi = ci[q]; }
            }
            for (int m = 1; m < 64; m <<= 1) {
                float ov = __shfl_xor(best, m, 64);
                int   oi = __shfl_xor(bi, m, 64);
                if (ov > best || (ov == best && oi < bi)) { best = ov; bi = oi; }
            }
            picks[c] = bi;
        }
        const float* hr = h_ws + (size_t)n * HD;
        float hv[8];
#pragma unroll
        for (int j = 0; j < 8; ++j) hv[j] = hr[lane * 8 + j];
        float s0 = 0.f, s1 = 0.f, s2 = 0.f, s3 = 0.f;
#pragma unroll
        for (int j = 0; j < 8; ++j) {
            size_t krow = (size_t)(lane * 8 + j) * VD;
            s0 = fmaf(hv[j], Wout[krow + picks[0]], s0);
            s1 = fmaf(hv[j], Wout[krow + picks[1]], s1);
            s2 = fmaf(hv[j], Wout[krow + picks[2]], s2);
            s3 = fmaf(hv[j], Wout[krow + picks[3]], s3);
        }
        for (int m = 1; m < 64; m <<= 1) {
            s0 += __shfl_xor(s0, m, 64);
            s1 += __shfl_xor(s1, m, 64);
            s2 += __shfl_xor(s2, m, 64);
            s3 += __shfl_xor(s3, m, 64);
        }
        if (lane == 0) {
            float pex[4] = {s0 + bout[picks[0]], s1 + bout[picks[1]],
                            s2 + bout[picks[2]], s3 + bout[picks[3]]};
            float best = pex[0]; int bi = picks[0];
            for (int c = 1; c < 4; ++c)
                if (pex[c] > best || (pex[c] == best && picks[c] < bi)) { best = pex[c]; bi = picks[c]; }
            tok_ws[n] = bi;
            out[n * TS + t] = bi;
        }
    } else {
        // ---- hua body (verbatim round-3 k_hua) for b = blk - 64 ----
        int b = blk - 64;
        int lane16 = tid & 15, rowg = tid >> 4;
        int s = b & 7, jt = b >> 3;
        int jb = jt * 64, kbase = s * 64;
        float acc[4][4] = {};
        for (int it = 0; it < 4; ++it) {
            int k4 = tid & 15;
            int nrow = (tid >> 4) + it * 16;
            float4 v = *(const float4*)&h_ws[nrow * 512 + kbase + k4 * 4];
            int col = (nrow + k4 * 4) & 63;
            xt[(k4 * 4 + 0) * 64 + col] = v.x;
            xt[(k4 * 4 + 1) * 64 + col] = v.y;
            xt[(k4 * 4 + 2) * 64 + col] = v.z;
            xt[(k4 * 4 + 3) * 64 + col] = v.w;
        }
        for (int it = 0; it < 4; ++it) {
            int r = it * 16 + (tid >> 4);
            int c4 = (tid & 15) * 4;
            *(float4*)&us[r * 68 + c4] = *(const float4*)&Ua[(size_t)(kbase + r) * 512 + jb + c4];
        }
        __syncthreads();
#pragma unroll 8
        for (int kk = 0; kk < 64; ++kk) {
            float4 w4 = *(const float4*)&us[kk * 68 + lane16 * 4];
            float4 h4 = *(const float4*)&xt[kk * 64 + ((rowg * 4 + (kk & ~3)) & 63)];
            float hv[4] = {h4.x, h4.y, h4.z, h4.w};
            float wv[4] = {w4.x, w4.y, w4.z, w4.w};
#pragma unroll
            for (int r = 0; r < 4; ++r)
#pragma unroll
                for (int j = 0; j < 4; ++j) acc[r][j] = fmaf(hv[r], wv[j], acc[r][j]);
        }
        float* gp = hua_part + (size_t)s * NB * HD;
        for (int r = 0; r < 4; ++r) {
            float4 o = {acc[r][0], acc[r][1], acc[r][2], acc[r][3]};
            *(float4*)&gp[(size_t)(rowg * 4 + r) * 512 + jb + lane16 * 4] = o;
        }
    }
}

extern "C" void kernel_launch(void* const* d_in, const int* in_sizes, int n_in,
                              void* d_out, int out_size, void* d_ws, size_t ws_size,
                              hipStream_t stream) {
    const float* hl     = (const float*)d_in[0];
    const float* emb    = (const float*)d_in[1];
    const float* Wh0    = (const float*)d_in[2];
    const float* bh0    = (const float*)d_in[3];
    const float* Wc0    = (const float*)d_in[4];
    const float* bc0    = (const float*)d_in[5];
    const float* Wa     = (const float*)d_in[6];
    const float* Ua     = (const float*)d_in[7];
    const float* ba     = (const float*)d_in[8];
    const float* va     = (const float*)d_in[9];
    const float* Wb     = (const float*)d_in[10];
    const float* bb     = (const float*)d_in[11];
    const float* Wx     = (const float*)d_in[12];
    const float* Wh     = (const float*)d_in[13];
    const float* b_lstm = (const float*)d_in[14];
    const float* Wout   = (const float*)d_in[15];
    const float* bout   = (const float*)d_in[16];

    float* ws         = (float*)d_ws;
    float* hlwa       = ws;                          // 6422528
    float* h_ws       = ws + 6422528;                // 32768
    float* c_ws       = h_ws + 32768;                // 32768
    float* z_ws       = c_ws + 32768;                // 32768
    int*   tok_ws     = (int*)(z_ws + 32768);        // 64
    float* hua_part   = z_ws + 32768 + 64;           // 8*64*512 = 262144
    float* gates_part = hua_part + 262144;           // 8*64*2048 = 1048576
    float* pval       = gates_part + 1048576;        // 64*470 = 30080
    int*   pidx       = (int*)(pval + 64 * NC2);     // 30080
    unsigned short* hB    = (unsigned short*)(pval + 2 * 64 * NC2);          // 32768 u16
    unsigned short* WoutB = (unsigned short*)(pval + 2 * 64 * NC2 + 16384);  // 15.36M u16
    int*   out        = (int*)d_out;

    k_init<<<64, 256, 0, stream>>>(hl, Wh0, bh0, Wc0, bc0, h_ws, c_ws, tok_ws);
    k_wcvt<<<7500, 256, 0, stream>>>(Wout, WoutB);
    k_hlwa<<<dim3(196, 8), 256, 0, stream>>>(hl, Wa, hlwa);
    // prologue: attention pipeline for t=0
    k_hua<<<64, 256, 0, stream>>>(h_ws, Ua, hua_part);
    k_attz<<<64, 512, 0, stream>>>(hlwa, hua_part, ba, va, hl, h_ws, Wb, bb, z_ws);
    for (int t = 0; t < TS; ++t) {
        k_gates<<<256, 256, 0, stream>>>(z_ws, emb, tok_ws, h_ws, Wx, Wh, gates_part);
        k_lstm<<<128, 256, 0, stream>>>(gates_part, b_lstm, h_ws, c_ws, hB);
        k_logits<<<NBL, 256, 0, stream>>>(hB, WoutB, bout, pval, pidx);
        k_axhua<<<128, 256, 0, stream>>>(pval, pidx, h_ws, Wout, bout, tok_ws, out, t,
                                         Ua, hua_part);
        if (t < TS - 1)
            k_attz<<<64, 512, 0, stream>>>(hlwa, hua_part, ba, va, hl, h_ws, Wb, bb, z_ws);
    }
}

// Round 9
// 1766.133 us; speedup vs baseline: 4.6885x; 1.2546x over previous
//
#include <hip/hip_runtime.h>
#include <math.h>

#define NB   64      // batch
#define LL   196     // regions
#define AD   512     // image feat dim
#define HD   512     // hidden
#define VD   30000   // vocab
#define TS   20      // steps
#define G4   2048    // 4*H
#define NBL  235     // ceil(30000/128) logits tiles
#define NC2  (NBL * 2)   // top-2 candidates per tile per row = 470

typedef __bf16 bf16x8 __attribute__((ext_vector_type(8)));
typedef float  f32x4  __attribute__((ext_vector_type(4)));

__device__ __forceinline__ float fast_tanh(float x) {
    float e = __builtin_exp2f(x * 2.8853900817779268f);   // exp(2x)
    return 1.0f - 2.0f / (e + 1.0f);
}
__device__ __forceinline__ float fast_sigmoid(float x) {
    return 1.0f / (1.0f + __builtin_exp2f(-x * 1.4426950408889634f));
}
__device__ __forceinline__ float fast_exp(float x) {
    return __builtin_exp2f(x * 1.4426950408889634f);
}
__device__ __forceinline__ unsigned short f2bf(float f) {   // RNE fp32->bf16
    unsigned int u = __float_as_uint(f);
    u += 0x7fffu + ((u >> 16) & 1u);
    return (unsigned short)(u >> 16);
}
// async global->LDS DMA, 16B per lane; lds base must be wave-uniform
__device__ __forceinline__ void gload_lds16(const void* g, void* l) {
    __builtin_amdgcn_global_load_lds((const __attribute__((address_space(1))) void*)g,
                                     (__attribute__((address_space(3))) void*)l, 16, 0, 0);
}
// merge two (top1, top2) candidate pairs, tie-break: smaller index wins
__device__ __forceinline__ void top2_merge(float& v1, int& i1, float& v2, int& i2,
                                           float ov1, int oi1, float ov2, int oi2) {
    if (ov1 > v1 || (ov1 == v1 && oi1 < i1)) {
        float sv = v1; int si = i1;
        v1 = ov1; i1 = oi1;
        if (ov2 > sv || (ov2 == sv && oi2 < si)) { v2 = ov2; i2 = oi2; }
        else { v2 = sv; i2 = si; }
    } else {
        if (ov1 > v2 || (ov1 == v2 && oi1 < i2)) { v2 = ov1; i2 = oi1; }
    }
}

// ---------------- precompute: mean over L, h0/c0, tok init ----------------
__global__ void k_init(const float* __restrict__ hl, const float* __restrict__ Wh0,
                       const float* __restrict__ bh0, const float* __restrict__ Wc0,
                       const float* __restrict__ bc0, float* __restrict__ h_ws,
                       float* __restrict__ c_ws, int* __restrict__ tok_ws) {
    __shared__ float mean_s[AD];
    int n = blockIdx.x, tid = threadIdx.x;
    for (int a = tid; a < AD; a += 256) {
        float acc = 0.f;
        const float* p = hl + ((size_t)n * LL) * AD + a;
        for (int l = 0; l < LL; ++l) acc += p[(size_t)l * AD];
        mean_s[a] = acc / 196.0f;
    }
    __syncthreads();
    for (int hh = tid; hh < HD; hh += 256) {
        float ah = bh0[hh], ac = bc0[hh];
        for (int k = 0; k < AD; ++k) {
            float m = mean_s[k];
            ah = fmaf(m, Wh0[k * HD + hh], ah);
            ac = fmaf(m, Wc0[k * HD + hh], ac);
        }
        h_ws[n * HD + hh] = fast_tanh(ah);
        c_ws[n * HD + hh] = fast_tanh(ac);
    }
    if (tid == 0) tok_ws[n] = 1;  // START
}

// ---------------- precompute: hl_Wa = hl @ Wa  (12544x512 @ 512x512) ----------------
__global__ void k_hlwa(const float* __restrict__ Amat, const float* __restrict__ Bmat,
                       float* __restrict__ Cmat) {
    __shared__ __attribute__((aligned(16))) float xt[64 * 64];  // (k, m) skewed
    __shared__ __attribute__((aligned(16))) float bs[64 * 68];  // (k, j) stride-68
    int tid = threadIdx.x;
    int lane16 = tid & 15, rowg = tid >> 4;
    int m0 = blockIdx.x * 64, jb = blockIdx.y * 64;
    float acc[4][4] = {};
    for (int ch = 0; ch < 8; ++ch) {
        int kbase = ch * 64;
        __syncthreads();
        for (int it = 0; it < 4; ++it) {
            int k4 = tid & 15;
            int nrow = (tid >> 4) + it * 16;
            float4 v = *(const float4*)&Amat[(size_t)(m0 + nrow) * 512 + kbase + k4 * 4];
            int col = (nrow + k4 * 4) & 63;
            xt[(k4 * 4 + 0) * 64 + col] = v.x;
            xt[(k4 * 4 + 1) * 64 + col] = v.y;
            xt[(k4 * 4 + 2) * 64 + col] = v.z;
            xt[(k4 * 4 + 3) * 64 + col] = v.w;
        }
        for (int it = 0; it < 4; ++it) {
            int r = it * 16 + (tid >> 4);
            int c4 = (tid & 15) * 4;
            *(float4*)&bs[r * 68 + c4] = *(const float4*)&Bmat[(size_t)(kbase + r) * 512 + jb + c4];
        }
        __syncthreads();
#pragma unroll 8
        for (int kk = 0; kk < 64; ++kk) {
            float4 w4 = *(const float4*)&bs[kk * 68 + lane16 * 4];
            float4 h4 = *(const float4*)&xt[kk * 64 + ((rowg * 4 + (kk & ~3)) & 63)];
            float hv[4] = {h4.x, h4.y, h4.z, h4.w};
            float wv[4] = {w4.x, w4.y, w4.z, w4.w};
#pragma unroll
            for (int r = 0; r < 4; ++r)
#pragma unroll
                for (int j = 0; j < 4; ++j) acc[r][j] = fmaf(hv[r], wv[j], acc[r][j]);
        }
    }
    for (int r = 0; r < 4; ++r) {
        float4 o = {acc[r][0], acc[r][1], acc[r][2], acc[r][3]};
        *(float4*)&Cmat[(size_t)(m0 + rowg * 4 + r) * 512 + jb + lane16 * 4] = o;
    }
}

// ---------------- one-shot: pack Wout (fp32 [512][30000]) -> bf16 B-fragments ----------
__global__ void k_wcvt(const float* __restrict__ Wout, unsigned short* __restrict__ WoutB) {
    int id = blockIdx.x * 256 + threadIdx.x;      // 0 .. 1,920,000-1
    int lane = id & 63;
    int kb = (id >> 6) & 15;
    int vb = id >> 10;
    int v  = vb * 16 + (lane & 15);
    int k0 = kb * 32 + (lane >> 4) * 8;
    unsigned int pk[4];
#pragma unroll
    for (int p = 0; p < 4; ++p) {
        unsigned int lo = f2bf(Wout[(size_t)(k0 + 2 * p) * VD + v]);
        unsigned int hi = f2bf(Wout[(size_t)(k0 + 2 * p + 1) * VD + v]);
        pk[p] = lo | (hi << 16);
    }
    *(uint4*)&WoutB[(size_t)id * 8] = make_uint4(pk[0], pk[1], pk[2], pk[3]);
}

// ---------------- prologue: hua_part[s] = h @ Ua[kslice]  (K-split 8, Ua LDS-staged) ----------------
__global__ void k_hua(const float* __restrict__ h_ws, const float* __restrict__ Ua,
                      float* __restrict__ hua_part) {
    __shared__ __attribute__((aligned(16))) float xt[64 * 64];
    __shared__ __attribute__((aligned(16))) float us[64 * 68];
    int tid = threadIdx.x;
    int lane16 = tid & 15, rowg = tid >> 4;
    int s = blockIdx.x & 7, jt = blockIdx.x >> 3;
    int jb = jt * 64, kbase = s * 64;
    float acc[4][4] = {};
    for (int it = 0; it < 4; ++it) {
        int k4 = tid & 15;
        int nrow = (tid >> 4) + it * 16;
        float4 v = *(const float4*)&h_ws[nrow * 512 + kbase + k4 * 4];
        int col = (nrow + k4 * 4) & 63;
        xt[(k4 * 4 + 0) * 64 + col] = v.x;
        xt[(k4 * 4 + 1) * 64 + col] = v.y;
        xt[(k4 * 4 + 2) * 64 + col] = v.z;
        xt[(k4 * 4 + 3) * 64 + col] = v.w;
    }
    for (int it = 0; it < 4; ++it) {
        int r = it * 16 + (tid >> 4);
        int c4 = (tid & 15) * 4;
        *(float4*)&us[r * 68 + c4] = *(const float4*)&Ua[(size_t)(kbase + r) * 512 + jb + c4];
    }
    __syncthreads();
#pragma unroll 8
    for (int kk = 0; kk < 64; ++kk) {
        float4 w4 = *(const float4*)&us[kk * 68 + lane16 * 4];
        float4 h4 = *(const float4*)&xt[kk * 64 + ((rowg * 4 + (kk & ~3)) & 63)];
        float hv[4] = {h4.x, h4.y, h4.z, h4.w};
        float wv[4] = {w4.x, w4.y, w4.z, w4.w};
#pragma unroll
        for (int r = 0; r < 4; ++r)
#pragma unroll
            for (int j = 0; j < 4; ++j) acc[r][j] = fmaf(hv[r], wv[j], acc[r][j]);
    }
    float* gp = hua_part + (size_t)s * NB * HD;
    for (int r = 0; r < 4; ++r) {
        float4 o = {acc[r][0], acc[r][1], acc[r][2], acc[r][3]};
        *(float4*)&gp[(size_t)(rowg * 4 + r) * 512 + jb + lane16 * 4] = o;
    }
}

// ---------------- att_e body: e[n][l] = sum_h tanh(hlWa + hUa + ba) * va ----------------
// b in 0..255 -> n = b>>2, q = b&3 (round-3 verbatim, 4-way row split)
__device__ __forceinline__ void atte_body(int b, int tid,
        const float* __restrict__ hlwa, const float* __restrict__ hua_part,
        const float* __restrict__ ba, const float* __restrict__ va,
        float* __restrict__ e_ws) {
    int n = b >> 2, q = b & 3;
    int wave = tid >> 6, lane = tid & 63;
    float4 ua_a = *(const float4*)&ba[lane * 4];
    float4 ua_b = *(const float4*)&ba[256 + lane * 4];
    for (int s = 0; s < 8; ++s) {
        const float* p = hua_part + (size_t)s * NB * HD + n * HD;
        float4 pa = *(const float4*)&p[lane * 4];
        float4 pb = *(const float4*)&p[256 + lane * 4];
        ua_a.x += pa.x; ua_a.y += pa.y; ua_a.z += pa.z; ua_a.w += pa.w;
        ua_b.x += pb.x; ua_b.y += pb.y; ua_b.z += pb.z; ua_b.w += pb.w;
    }
    float4 va_a = *(const float4*)&va[lane * 4];
    float4 va_b = *(const float4*)&va[256 + lane * 4];
    for (int ll = wave; ll < 49; ll += 4) {
        int l = q * 49 + ll;
        const float* base = hlwa + ((size_t)n * LL + l) * HD;
        float4 xa = *(const float4*)&base[lane * 4];
        float4 xb = *(const float4*)&base[256 + lane * 4];
        float s = 0.f;
        s = fmaf(fast_tanh(xa.x + ua_a.x), va_a.x, s);
        s = fmaf(fast_tanh(xa.y + ua_a.y), va_a.y, s);
        s = fmaf(fast_tanh(xa.z + ua_a.z), va_a.z, s);
        s = fmaf(fast_tanh(xa.w + ua_a.w), va_a.w, s);
        s = fmaf(fast_tanh(xb.x + ua_b.x), va_b.x, s);
        s = fmaf(fast_tanh(xb.y + ua_b.y), va_b.y, s);
        s = fmaf(fast_tanh(xb.z + ua_b.z), va_b.z, s);
        s = fmaf(fast_tanh(xb.w + ua_b.w), va_b.w, s);
        for (int m = 1; m < 64; m <<= 1) s += __shfl_xor(s, m, 64);
        if (lane == 0) e_ws[n * LL + l] = s;
    }
}

// prologue-only wrapper (256 blocks)
__global__ void k_att_e(const float* __restrict__ hlwa, const float* __restrict__ hua_part,
                        const float* __restrict__ ba, const float* __restrict__ va,
                        float* __restrict__ e_ws) {
    atte_body(blockIdx.x, threadIdx.x, hlwa, hua_part, ba, va, e_ws);
}

// ---------------- per step: softmax over L, beta gate, z = (alpha @ hl) * beta ----------------
__global__ void k_soft_z(const float* __restrict__ e_ws, const float* __restrict__ hl,
                         const float* __restrict__ h_ws, const float* __restrict__ Wb,
                         const float* __restrict__ bb, float* __restrict__ z_ws) {
    __shared__ float red[256];
    __shared__ float alpha[256];
    __shared__ float zs[512];
    __shared__ float beta_s;
    int n = blockIdx.x, tid = threadIdx.x;
    float ev = (tid < LL) ? e_ws[n * LL + tid] : -INFINITY;
    red[tid] = ev;
    __syncthreads();
    for (int s = 128; s > 0; s >>= 1) {
        if (tid < s) red[tid] = fmaxf(red[tid], red[tid + s]);
        __syncthreads();
    }
    float m = red[0];
    __syncthreads();
    float a = (tid < LL) ? fast_exp(ev - m) : 0.f;
    red[tid] = a;
    __syncthreads();
    for (int s = 128; s > 0; s >>= 1) {
        if (tid < s) red[tid] += red[tid + s];
        __syncthreads();
    }
    float sum = red[0];
    alpha[tid] = a / sum;
    __syncthreads();
    float bp = h_ws[n * HD + tid] * Wb[tid] + h_ws[n * HD + 256 + tid] * Wb[256 + tid];
    red[tid] = bp;
    __syncthreads();
    for (int s = 128; s > 0; s >>= 1) {
        if (tid < s) red[tid] += red[tid + s];
        __syncthreads();
    }
    if (tid == 0) beta_s = fast_sigmoid(red[0] + bb[0]);
    int lq = tid >> 7, ai = tid & 127;
    const float* base = hl + ((size_t)n * LL) * AD + ai * 4;
    float4 acc4 = {0.f, 0.f, 0.f, 0.f};
    int l0 = lq * 98, l1 = l0 + 98;
    for (int l = l0; l < l1; ++l) {
        float al = alpha[l];
        float4 v = *(const float4*)&base[(size_t)l * AD];
        acc4.x = fmaf(al, v.x, acc4.x);
        acc4.y = fmaf(al, v.y, acc4.y);
        acc4.z = fmaf(al, v.z, acc4.z);
        acc4.w = fmaf(al, v.w, acc4.w);
    }
    if (lq == 1) *(float4*)&zs[ai * 4] = acc4;
    __syncthreads();
    if (lq == 0) {
        float4 o = *(const float4*)&zs[ai * 4];
        float b = beta_s;
        o.x = (o.x + acc4.x) * b;
        o.y = (o.y + acc4.y) * b;
        o.z = (o.z + acc4.z) * b;
        o.w = (o.w + acc4.w) * b;
        *(float4*)&z_ws[n * AD + ai * 4] = o;
    }
}

// ---------------- per step: gates partial GEMM  X[64x1536] @ W[1536x2048], K split 8 ----------------
__global__ void k_gates(const float* __restrict__ z_ws, const float* __restrict__ emb,
                        const int* __restrict__ tok_ws, const float* __restrict__ h_ws,
                        const float* __restrict__ Wx, const float* __restrict__ Wh,
                        float* __restrict__ gates_part) {
    __shared__ __attribute__((aligned(16))) float xt[64 * 64];
    __shared__ __attribute__((aligned(16))) float wsl[64 * 68];
    int tid = threadIdx.x;
    int lane16 = tid & 15, rowg = tid >> 4;
    int s = blockIdx.x & 7, jt = blockIdx.x >> 3;
    int jb = jt * 64;
    float acc[4][4] = {};
    for (int ch = 0; ch < 3; ++ch) {
        int kbase = s * 192 + ch * 64;
        __syncthreads();
        for (int it = 0; it < 4; ++it) {
            int nrow = (tid >> 4) + it * 16;
            int k4 = tid & 15;
            int gk = kbase + k4 * 4;
            const float* src;
            if (gk < 512)       src = &z_ws[nrow * 512 + gk];
            else if (gk < 1024) src = &emb[(size_t)tok_ws[nrow] * 512 + (gk - 512)];
            else                src = &h_ws[nrow * 512 + (gk - 1024)];
            float4 v = *(const float4*)src;
            int col = (nrow + k4 * 4) & 63;
            xt[(k4 * 4 + 0) * 64 + col] = v.x;
            xt[(k4 * 4 + 1) * 64 + col] = v.y;
            xt[(k4 * 4 + 2) * 64 + col] = v.z;
            xt[(k4 * 4 + 3) * 64 + col] = v.w;
        }
        for (int it = 0; it < 4; ++it) {
            int r = it * 16 + (tid >> 4);
            int gk = kbase + r;
            const float* wrow = (gk < 1024) ? &Wx[(size_t)gk * G4] : &Wh[(size_t)(gk - 1024) * G4];
            int c4 = (tid & 15) * 4;
            *(float4*)&wsl[r * 68 + c4] = *(const float4*)&wrow[jb + c4];
        }
        __syncthreads();
#pragma unroll 8
        for (int kk = 0; kk < 64; ++kk) {
            float4 w4 = *(const float4*)&wsl[kk * 68 + lane16 * 4];
            float4 h4 = *(const float4*)&xt[kk * 64 + ((rowg * 4 + (kk & ~3)) & 63)];
            float hv[4] = {h4.x, h4.y, h4.z, h4.w};
            float wv[4] = {w4.x, w4.y, w4.z, w4.w};
#pragma unroll
            for (int r = 0; r < 4; ++r)
#pragma unroll
                for (int j = 0; j < 4; ++j) acc[r][j] = fmaf(hv[r], wv[j], acc[r][j]);
        }
    }
    float* gp = gates_part + (size_t)s * NB * G4;
    for (int r = 0; r < 4; ++r) {
        float4 o = {acc[r][0], acc[r][1], acc[r][2], acc[r][3]};
        *(float4*)&gp[(size_t)(rowg * 4 + r) * G4 + jb + lane16 * 4] = o;
    }
}

// ---------------- per step: reduce gate partials + LSTM cell update (+ bf16 h pack) ----------------
__global__ void k_lstm(const float* __restrict__ gates_part, const float* __restrict__ b_lstm,
                       float* __restrict__ h_ws, float* __restrict__ c_ws,
                       unsigned short* __restrict__ hB) {
    int idx = blockIdx.x * 256 + threadIdx.x;  // 0..32767
    int n = idx >> 9, hh = idx & 511;
    float ig = b_lstm[hh], fg = b_lstm[512 + hh], gg = b_lstm[1024 + hh], og = b_lstm[1536 + hh];
    for (int s = 0; s < 8; ++s) {
        const float* gp = gates_part + (size_t)s * NB * G4 + (size_t)n * G4;
        ig += gp[hh]; fg += gp[512 + hh]; gg += gp[1024 + hh]; og += gp[1536 + hh];
    }
    float c = c_ws[idx];
    float cn = fast_sigmoid(fg) * c + fast_sigmoid(ig) * fast_tanh(gg);
    float hn = fast_sigmoid(og) * fast_tanh(cn);
    c_ws[idx] = cn;
    h_ws[idx] = hn;
    // pack h into bf16 A-fragment layout [mb(4)][kb(16)][lane(64)][j(8)]
    int mb = n >> 4, kb = hh >> 5;
    int lane = (n & 15) + ((hh >> 3) & 3) * 16;
    hB[(((size_t)mb * 16 + kb) * 64 + lane) * 8 + (hh & 7)] = f2bf(hn);
}

// ---------------- per step (fused): logits(t) [blocks 0..234] || hua(t+1) [blocks 235..298] ----
// both depend only on lstm(t): logits reads hB/WoutB, writes pval/pidx;
// hua reads h_ws(=h(t+1))/Ua, writes hua_part (last read by att_e(t) in the PREVIOUS axatte).
__global__ void k_loghua(const unsigned short* __restrict__ hB,
                         const unsigned short* __restrict__ WoutB,
                         const float* __restrict__ bout,
                         float* __restrict__ pval, int* __restrict__ pidx,
                         const float* __restrict__ h_ws, const float* __restrict__ Ua,
                         float* __restrict__ hua_part) {
    __shared__ __attribute__((aligned(16))) char smem[69632];   // union: logits 68KB / hua 33KB
    int blk = blockIdx.x, tid = threadIdx.x;
    if (blk < NBL) {
        // ---- logits body (round-8 k_logits verbatim; sv/si flat-indexed) ----
        unsigned short* hs = (unsigned short*)smem;           // 64KB, fragment-linear
        float* sv1 = (float*)(smem + 65536);
        float* sv2 = (float*)(smem + 66560);
        int*   si1 = (int*)(smem + 67584);
        int*   si2 = (int*)(smem + 68608);
        int w = tid >> 6, lane = tid & 63;
        int jb = blk * 128;
        if (jb > VD - 128) jb = VD - 128;        // clamp last tile (dups deduped later)
#pragma unroll
        for (int i = 0; i < 16; ++i) {
            int base = i * 256 + w * 64;         // 16B-slot index
            gload_lds16(&hB[(size_t)(base + lane) * 8], &hs[(size_t)base * 8]);
        }
        __syncthreads();                         // drains DMA
        int vbw = (jb >> 4) + w * 2;             // this wave's first vb tile
        const bf16x8* wP = (const bf16x8*)WoutB;
        const bf16x8* hP = (const bf16x8*)hs;
        f32x4 acc[2][4] = {};                    // [vbi][mbi]
#pragma unroll 2
        for (int kb = 0; kb < 16; ++kb) {
            bf16x8 b0 = wP[((size_t)vbw * 16 + kb) * 64 + lane];
            bf16x8 b1 = wP[((size_t)(vbw + 1) * 16 + kb) * 64 + lane];
            bf16x8 a0 = hP[(0 * 16 + kb) * 64 + lane];
            bf16x8 a1 = hP[(1 * 16 + kb) * 64 + lane];
            bf16x8 a2 = hP[(2 * 16 + kb) * 64 + lane];
            bf16x8 a3 = hP[(3 * 16 + kb) * 64 + lane];
            acc[0][0] = __builtin_amdgcn_mfma_f32_16x16x32_bf16(a0, b0, acc[0][0], 0, 0, 0);
            acc[0][1] = __builtin_amdgcn_mfma_f32_16x16x32_bf16(a1, b0, acc[0][1], 0, 0, 0);
            acc[0][2] = __builtin_amdgcn_mfma_f32_16x16x32_bf16(a2, b0, acc[0][2], 0, 0, 0);
            acc[0][3] = __builtin_amdgcn_mfma_f32_16x16x32_bf16(a3, b0, acc[0][3], 0, 0, 0);
            acc[1][0] = __builtin_amdgcn_mfma_f32_16x16x32_bf16(a0, b1, acc[1][0], 0, 0, 0);
            acc[1][1] = __builtin_amdgcn_mfma_f32_16x16x32_bf16(a1, b1, acc[1][1], 0, 0, 0);
            acc[1][2] = __builtin_amdgcn_mfma_f32_16x16x32_bf16(a2, b1, acc[1][2], 0, 0, 0);
            acc[1][3] = __builtin_amdgcn_mfma_f32_16x16x32_bf16(a3, b1, acc[1][3], 0, 0, 0);
        }
        float bo0 = bout[vbw * 16 + (lane & 15)];
        float bo1 = bout[(vbw + 1) * 16 + (lane & 15)];
        int colb = vbw * 16 + (lane & 15);
        int g = lane >> 4;
#pragma unroll
        for (int mbi = 0; mbi < 4; ++mbi) {
#pragma unroll
            for (int r = 0; r < 4; ++r) {
                int row = mbi * 16 + g * 4 + r;  // C/D: row=(l>>4)*4+reg, col=l&15 (m89)
                float v1 = acc[0][mbi][r] + bo0; int i1 = colb;
                float v2 = acc[1][mbi][r] + bo1; int i2 = colb + 16;
                if (v2 > v1 || (v2 == v1 && i2 < i1)) {
                    float tv = v1; int ti = i1; v1 = v2; i1 = i2; v2 = tv; i2 = ti;
                }
                for (int m = 1; m < 16; m <<= 1) {
                    float ov1 = __shfl_xor(v1, m, 64); int oi1 = __shfl_xor(i1, m, 64);
                    float ov2 = __shfl_xor(v2, m, 64); int oi2 = __shfl_xor(i2, m, 64);
                    top2_merge(v1, i1, v2, i2, ov1, oi1, ov2, oi2);
                }
                if ((lane & 15) == 0) {
                    sv1[w * 64 + row] = v1; si1[w * 64 + row] = i1;
                    sv2[w * 64 + row] = v2; si2[w * 64 + row] = i2;
                }
            }
        }
        __syncthreads();
        if (tid < 64) {                          // cross-wave merge -> block top-2 per row
            float v1 = sv1[tid]; int i1 = si1[tid];
            float v2 = sv2[tid]; int i2 = si2[tid];
            for (int q = 1; q < 4; ++q)
                top2_merge(v1, i1, v2, i2, sv1[q * 64 + tid], si1[q * 64 + tid],
                           sv2[q * 64 + tid], si2[q * 64 + tid]);
            pval[(size_t)tid * NC2 + blk * 2 + 0] = v1;
            pval[(size_t)tid * NC2 + blk * 2 + 1] = v2;
            pidx[(size_t)tid * NC2 + blk * 2 + 0] = i1;
            pidx[(size_t)tid * NC2 + blk * 2 + 1] = i2;
        }
    } else {
        // ---- hua body (round-3 k_hua verbatim) for b = blk - NBL ----
        float* xt = (float*)smem;                // 16KB
        float* us = (float*)(smem + 16384);      // 17KB
        int b = blk - NBL;
        int lane16 = tid & 15, rowg = tid >> 4;
        int s = b & 7, jt = b >> 3;
        int jb = jt * 64, kbase = s * 64;
        float acc[4][4] = {};
        for (int it = 0; it < 4; ++it) {
            int k4 = tid & 15;
            int nrow = (tid >> 4) + it * 16;
            float4 v = *(const float4*)&h_ws[nrow * 512 + kbase + k4 * 4];
            int col = (nrow + k4 * 4) & 63;
            xt[(k4 * 4 + 0) * 64 + col] = v.x;
            xt[(k4 * 4 + 1) * 64 + col] = v.y;
            xt[(k4 * 4 + 2) * 64 + col] = v.z;
            xt[(k4 * 4 + 3) * 64 + col] = v.w;
        }
        for (int it = 0; it < 4; ++it) {
            int r = it * 16 + (tid >> 4);
            int c4 = (tid & 15) * 4;
            *(float4*)&us[r * 68 + c4] = *(const float4*)&Ua[(size_t)(kbase + r) * 512 + jb + c4];
        }
        __syncthreads();
#pragma unroll 8
        for (int kk = 0; kk < 64; ++kk) {
            float4 w4 = *(const float4*)&us[kk * 68 + lane16 * 4];
            float4 h4 = *(const float4*)&xt[kk * 64 + ((rowg * 4 + (kk & ~3)) & 63)];
            float hv[4] = {h4.x, h4.y, h4.z, h4.w};
            float wv[4] = {w4.x, w4.y, w4.z, w4.w};
#pragma unroll
            for (int r = 0; r < 4; ++r)
#pragma unroll
                for (int j = 0; j < 4; ++j) acc[r][j] = fmaf(hv[r], wv[j], acc[r][j]);
        }
        float* gp = hua_part + (size_t)s * NB * HD;
        for (int r = 0; r < 4; ++r) {
            float4 o = {acc[r][0], acc[r][1], acc[r][2], acc[r][3]};
            *(float4*)&gp[(size_t)(rowg * 4 + r) * 512 + jb + lane16 * 4] = o;
        }
    }
}

// ---------------- per step (fused): argmax(t) [blocks 0..63] || att_e(t+1) [blocks 64..319] ----
// both depend only on loghua(t): argmax reads pval/pidx/h_ws/Wout -> tok_ws/out;
// att_e reads hlwa/hua_part(t+1)/ba/va -> e_ws. Host launches 64 blocks at t=TS-1.
__global__ void k_axatte(const float* __restrict__ pval, const int* __restrict__ pidx,
                         const float* __restrict__ h_ws, const float* __restrict__ Wout,
                         const float* __restrict__ bout, int* __restrict__ tok_ws,
                         int* __restrict__ out, int t,
                         const float* __restrict__ hlwa, const float* __restrict__ hua_part,
                         const float* __restrict__ ba, const float* __restrict__ va,
                         float* __restrict__ e_ws) {
    int blk = blockIdx.x, tid = threadIdx.x;
    if (blk >= 64) {
        atte_body(blk - 64, tid, hlwa, hua_part, ba, va, e_ws);
        return;
    }
    // ---- argmax body (round-3 verbatim; wave 0 only, no barriers) ----
    if (tid >= 64) return;
    int n = blk, lane = tid;
    const float* pv = pval + (size_t)n * NC2;
    const int*   pi = pidx + (size_t)n * NC2;
    float cv[8]; int ci[8];
#pragma unroll
    for (int q = 0; q < 8; ++q) {
        int i = q * 64 + lane;
        bool ok = i < NC2;
        cv[q] = ok ? pv[i] : -INFINITY;
        ci[q] = ok ? pi[i] : 0x7fffffff;
    }
    int picks[4];
#pragma unroll
    for (int c = 0; c < 4; ++c) {
        float best = -INFINITY; int bi = 0x7fffffff;
#pragma unroll
        for (int q = 0; q < 8; ++q) {
            bool skip = false;
#pragma unroll
            for (int p = 0; p < 4; ++p) skip = skip || (p < c && ci[q] == picks[p]);
            if (!skip && (cv[q] > best || (cv[q] == best && ci[q] < bi))) { best = cv[q]; bi = ci[q]; }
        }
        for (int m = 1; m < 64; m <<= 1) {
            float ov = __shfl_xor(best, m, 64);
            int   oi = __shfl_xor(bi, m, 64);
            if (ov > best || (ov == best && oi < bi)) { best = ov; bi = oi; }
        }
        picks[c] = bi;
    }
    const float* hr = h_ws + (size_t)n * HD;
    float hv[8];
#pragma unroll
    for (int j = 0; j < 8; ++j) hv[j] = hr[lane * 8 + j];
    float s0 = 0.f, s1 = 0.f, s2 = 0.f, s3 = 0.f;
#pragma unroll
    for (int j = 0; j < 8; ++j) {
        size_t krow = (size_t)(lane * 8 + j) * VD;
        s0 = fmaf(hv[j], Wout[krow + picks[0]], s0);
        s1 = fmaf(hv[j], Wout[krow + picks[1]], s1);
        s2 = fmaf(hv[j], Wout[krow + picks[2]], s2);
        s3 = fmaf(hv[j], Wout[krow + picks[3]], s3);
    }
    for (int m = 1; m < 64; m <<= 1) {
        s0 += __shfl_xor(s0, m, 64);
        s1 += __shfl_xor(s1, m, 64);
        s2 += __shfl_xor(s2, m, 64);
        s3 += __shfl_xor(s3, m, 64);
    }
    if (lane == 0) {
        float pex[4] = {s0 + bout[picks[0]], s1 + bout[picks[1]],
                        s2 + bout[picks[2]], s3 + bout[picks[3]]};
        float best = pex[0]; int bi = picks[0];
        for (int c = 1; c < 4; ++c)
            if (pex[c] > best || (pex[c] == best && picks[c] < bi)) { best = pex[c]; bi = picks[c]; }
        tok_ws[n] = bi;
        out[n * TS + t] = bi;
    }
}

extern "C" void kernel_launch(void* const* d_in, const int* in_sizes, int n_in,
                              void* d_out, int out_size, void* d_ws, size_t ws_size,
                              hipStream_t stream) {
    const float* hl     = (const float*)d_in[0];
    const float* emb    = (const float*)d_in[1];
    const float* Wh0    = (const float*)d_in[2];
    const float* bh0    = (const float*)d_in[3];
    const float* Wc0    = (const float*)d_in[4];
    const float* bc0    = (const float*)d_in[5];
    const float* Wa     = (const float*)d_in[6];
    const float* Ua     = (const float*)d_in[7];
    const float* ba     = (const float*)d_in[8];
    const float* va     = (const float*)d_in[9];
    const float* Wb     = (const float*)d_in[10];
    const float* bb     = (const float*)d_in[11];
    const float* Wx     = (const float*)d_in[12];
    const float* Wh     = (const float*)d_in[13];
    const float* b_lstm = (const float*)d_in[14];
    const float* Wout   = (const float*)d_in[15];
    const float* bout   = (const float*)d_in[16];

    float* ws         = (float*)d_ws;
    float* hlwa       = ws;                          // 6422528
    float* h_ws       = ws + 6422528;                // 32768
    float* c_ws       = h_ws + 32768;                // 32768
    float* z_ws       = c_ws + 32768;                // 32768
    float* e_ws       = z_ws + 32768;                // 12544
    int*   tok_ws     = (int*)(e_ws + 12544);        // 64
    float* hua_part   = e_ws + 12544 + 64;           // 8*64*512 = 262144
    float* gates_part = hua_part + 262144;           // 8*64*2048 = 1048576
    float* pval       = gates_part + 1048576;        // 64*470 = 30080
    int*   pidx       = (int*)(pval + 64 * NC2);     // 30080
    unsigned short* hB    = (unsigned short*)(pval + 2 * 64 * NC2);          // 32768 u16
    unsigned short* WoutB = (unsigned short*)(pval + 2 * 64 * NC2 + 16384);  // 15.36M u16
    int*   out        = (int*)d_out;

    k_init<<<64, 256, 0, stream>>>(hl, Wh0, bh0, Wc0, bc0, h_ws, c_ws, tok_ws);
    k_wcvt<<<7500, 256, 0, stream>>>(Wout, WoutB);
    k_hlwa<<<dim3(196, 8), 256, 0, stream>>>(hl, Wa, hlwa);
    // prologue: attention pipeline for t=0
    k_hua<<<64, 256, 0, stream>>>(h_ws, Ua, hua_part);
    k_att_e<<<256, 256, 0, stream>>>(hlwa, hua_part, ba, va, e_ws);
    k_soft_z<<<64, 256, 0, stream>>>(e_ws, hl, h_ws, Wb, bb, z_ws);
    for (int t = 0; t < TS; ++t) {
        k_gates<<<256, 256, 0, stream>>>(z_ws, emb, tok_ws, h_ws, Wx, Wh, gates_part);
        k_lstm<<<128, 256, 0, stream>>>(gates_part, b_lstm, h_ws, c_ws, hB);
        k_loghua<<<NBL + 64, 256, 0, stream>>>(hB, WoutB, bout, pval, pidx,
                                               h_ws, Ua, hua_part);
        k_axatte<<<(t == TS - 1) ? 64 : 320, 256, 0, stream>>>(
            pval, pidx, h_ws, Wout, bout, tok_ws, out, t,
            hlwa, hua_part, ba, va, e_ws);
        if (t < TS - 1)
            k_soft_z<<<64, 256, 0, stream>>>(e_ws, hl, h_ws, Wb, bb, z_ws);
    }
}